// Round 1
// baseline (444.676 us; speedup 1.0000x reference)
//
#include <hip/hip_runtime.h>

typedef unsigned short u16;
typedef unsigned int u32;
typedef __attribute__((ext_vector_type(8))) short short8;  // 8 bf16 = 4 VGPR (MFMA A/B frag)
typedef __attribute__((ext_vector_type(4))) float f32x4;   // MFMA C/D frag

#define T_LEN 4096
#define BATCH 4
#define M_TOT (BATCH*T_LEN)   /* 16384 rows */
#define NCHUNK 32
#define CLEN 128              /* 4096/32 */

__device__ __forceinline__ u16 f2bf(float f){
  u32 u = __builtin_bit_cast(u32, f);
  u32 r = (u + 0x7FFFu + ((u >> 16) & 1u)) >> 16;   // RTN-even
  return (u16)r;
}
__device__ __forceinline__ float bf2f(u16 h){
  u32 u = ((u32)h) << 16; return __builtin_bit_cast(float, u);
}
__device__ __forceinline__ float sigmoid_(float v){ return 1.f/(1.f + __expf(-v)); }
// pi * tanh(v) = pi * (1 - 2/(exp(2v)+1)); robust at +-inf via expf saturation
__device__ __forceinline__ float tanh_pi_(float v){
  return 3.14159265358979323846f * (1.f - 2.f/(1.f + __expf(2.f*v)));
}

// ---------------- fp32 -> bf16 convert (vectorized x4) ----------------
__global__ __launch_bounds__(256) void cvt_bf16_k(const float* __restrict__ in,
                                                  u16* __restrict__ out, int n4){
  int g = blockIdx.x*256 + threadIdx.x;
  if (g >= n4) return;
  float4 v = reinterpret_cast<const float4*>(in)[g];
  reinterpret_cast<ushort4*>(out)[g] =
      make_ushort4(f2bf(v.x), f2bf(v.y), f2bf(v.z), f2bf(v.w));
}

// ---------------- bf16 GEMM: C[M,N] = A[M,K] @ B[N,K]^T ----------------
// m97 structure: 128x128 tile, BK=64, 4 waves (2x2), global_load_lds width 16.
// EPI 0: GEMM1 -> fp32 activated res (col<1024: pi*tanh, else sigmoid)
// EPI 1: GEMM2 -> bf16 silu(v + bias)
// EPI 2: GEMM3 -> fp32 v + bias
template<int EPI>
__global__ __launch_bounds__(256, 3) void gemm_bt(
    const u16* __restrict__ A, const u16* __restrict__ B,
    const float* __restrict__ bias, void* __restrict__ Cout,
    int M, int N, int K)
{
  constexpr int BM=128, BN=128, BK=64;
  __shared__ __attribute__((aligned(16))) u16 lA[BM*BK];
  __shared__ __attribute__((aligned(16))) u16 lB[BN*BK];
  const int tid  = threadIdx.x;
  const int wid  = tid >> 6, lane = tid & 63;
  const int nbn  = N / BN;
  const int bm   = blockIdx.x / nbn, bn = blockIdx.x % nbn;
  const int wr   = wid >> 1, wc = wid & 1;       // wave 64x64 subtile
  const int fr   = lane & 15, fq = lane >> 4;    // frag row / k-group
  const int srow = lane >> 3, scol = (lane & 7)*8; // staging lane offsets

  f32x4 acc[4][4];
#pragma unroll
  for (int m=0;m<4;m++)
#pragma unroll
    for (int n=0;n<4;n++) acc[m][n] = f32x4{0.f,0.f,0.f,0.f};

  const size_t abase = (size_t)bm*BM;
  const size_t bbase = (size_t)bn*BN;

  for (int kt=0; kt<K; kt+=BK){
    // stage A tile (16KB): 16 chunks of 1KB; wave wid takes chunks i*4+wid
#pragma unroll
    for (int i=0;i<4;i++){
      const int c = i*4 + wid;
      const u16* s = A + (abase + (size_t)(c*8 + srow))*K + kt + scol;
      __builtin_amdgcn_global_load_lds(
          (const __attribute__((address_space(1))) void*)s,
          (__attribute__((address_space(3))) void*)&lA[c*512], 16, 0, 0);
    }
#pragma unroll
    for (int i=0;i<4;i++){
      const int c = i*4 + wid;
      const u16* s = B + (bbase + (size_t)(c*8 + srow))*K + kt + scol;
      __builtin_amdgcn_global_load_lds(
          (const __attribute__((address_space(1))) void*)s,
          (__attribute__((address_space(3))) void*)&lB[c*512], 16, 0, 0);
    }
    __syncthreads();
#pragma unroll
    for (int kk=0; kk<2; kk++){
      short8 af[4], bf[4];
#pragma unroll
      for (int m=0;m<4;m++)
        af[m] = *reinterpret_cast<const short8*>(&lA[(wr*64 + m*16 + fr)*BK + kk*32 + fq*8]);
#pragma unroll
      for (int n=0;n<4;n++)
        bf[n] = *reinterpret_cast<const short8*>(&lB[(wc*64 + n*16 + fr)*BK + kk*32 + fq*8]);
#pragma unroll
      for (int m=0;m<4;m++)
#pragma unroll
        for (int n=0;n<4;n++)
          acc[m][n] = __builtin_amdgcn_mfma_f32_16x16x32_bf16(af[m], bf[n], acc[m][n], 0,0,0);
    }
    __syncthreads();
  }

  // epilogue: D[i][j] -> row = fq*4 + r, col = fr  (m89-verified mapping)
  const int orow0 = bm*BM + wr*64;
  const int ocol0 = bn*BN + wc*64;
#pragma unroll
  for (int m=0;m<4;m++){
#pragma unroll
    for (int n=0;n<4;n++){
      const int col = ocol0 + n*16 + fr;
#pragma unroll
      for (int r=0;r<4;r++){
        const int row = orow0 + m*16 + fq*4 + r;
        float v = acc[m][n][r];
        if constexpr (EPI == 0){
          float o = (col < 1024) ? tanh_pi_(v) : sigmoid_(v);
          ((float*)Cout)[(size_t)row*N + col] = o;
        } else if constexpr (EPI == 1){
          v += bias[col];
          ((u16*)Cout)[(size_t)row*N + col] = f2bf(v * sigmoid_(v));
        } else {
          v += bias[col];
          ((float*)Cout)[(size_t)row*N + col] = v;
        }
      }
    }
  }
}

// ---------------- chunked lerp scan ----------------
// res layout: [b][t][2048], col<1024 = theta' (pi*tanh), col>=1024 = s (sigmoid)
// recurrence: h_t = (1-s_t) h_{t-1} + s_t * theta'_t, h_{-1} = 0
__global__ __launch_bounds__(256) void scan_stage1(const float* __restrict__ res,
                                                   float* __restrict__ sA,
                                                   float* __restrict__ sB){
  const int c     = (blockIdx.x & 3)*256 + threadIdx.x;
  const int chunk = (blockIdx.x >> 2) & (NCHUNK-1);
  const int b     = blockIdx.x >> 7;
  const float* p = res + ((size_t)(b*T_LEN + chunk*CLEN))*2048 + c;
  float A = 1.f, Bv = 0.f;
#pragma unroll 4
  for (int t=0;t<CLEN;++t){
    float th = p[0];
    float s  = p[1024];
    float a  = 1.f - s;
    A  *= a;
    Bv  = a*Bv + s*th;
    p  += 2048;
  }
  const int idx = (b*NCHUNK + chunk)*1024 + c;
  sA[idx] = A; sB[idx] = Bv;
}

__global__ __launch_bounds__(256) void scan_stage2(const float* __restrict__ sA,
                                                   const float* __restrict__ sB,
                                                   float* __restrict__ Hp){
  const int g = blockIdx.x*256 + threadIdx.x;   // 4096 threads: b*1024+c
  const int b = g >> 10, c = g & 1023;
  float H = 0.f;
#pragma unroll
  for (int i=0;i<NCHUNK;++i){
    const int idx = (b*NCHUNK + i)*1024 + c;
    Hp[idx] = H;                 // state BEFORE chunk i
    H = sA[idx]*H + sB[idx];
  }
}

__global__ __launch_bounds__(256) void scan_stage3(const float* __restrict__ res,
                                                   const float* __restrict__ Hp,
                                                   float* __restrict__ h){
  const int c     = (blockIdx.x & 3)*256 + threadIdx.x;
  const int chunk = (blockIdx.x >> 2) & (NCHUNK-1);
  const int b     = blockIdx.x >> 7;
  const float* p = res + ((size_t)(b*T_LEN + chunk*CLEN))*2048 + c;
  float*       q = h   + ((size_t)(b*T_LEN + chunk*CLEN))*1024 + c;
  float H = Hp[(b*NCHUNK + chunk)*1024 + c];
#pragma unroll 4
  for (int t=0;t<CLEN;++t){
    float th = p[0];
    float s  = p[1024];
    H = (1.f - s)*H + s*th;
    q[0] = H;
    p += 2048; q += 1024;
  }
}

// ---------------- depthwise causal conv(3) + residual -> bf16 z ----------------
// conv[t] = h[t-2]*w0 + h[t-1]*w1 + h[t]*w2 ; z = h + conv + conv_b
__global__ __launch_bounds__(256) void conv_z_k(const float* __restrict__ h,
                                                const float* __restrict__ cw,
                                                const float* __restrict__ cb,
                                                u16* __restrict__ z){
  const int g = blockIdx.x*256 + threadIdx.x;
  const int c = g & 1023;
  const int t = (g >> 10) & (T_LEN-1);
  float h0  = h[g];
  float hm1 = (t >= 1) ? h[g-1024] : 0.f;
  float hm2 = (t >= 2) ? h[g-2048] : 0.f;
  float v = h0 + cb[c] + hm2*cw[3*c] + hm1*cw[3*c+1] + h0*cw[3*c+2];
  z[g] = f2bf(v);
}

// ---------------- in-place row RMSNorm (d=1024, one block per row) ----------------
__global__ __launch_bounds__(256) void rmsnorm_k(float* __restrict__ io,
                                                 const float* __restrict__ w){
  const int row = blockIdx.x;
  const int tid = threadIdx.x;
  float* p = io + (size_t)row*1024;
  float4 v = reinterpret_cast<const float4*>(p)[tid];
  float ss = v.x*v.x + v.y*v.y + v.z*v.z + v.w*v.w;
#pragma unroll
  for (int o=32; o>0; o>>=1) ss += __shfl_xor(ss, o, 64);
  __shared__ float red[4];
  if ((tid & 63) == 0) red[tid >> 6] = ss;
  __syncthreads();
  float tot = red[0] + red[1] + red[2] + red[3];
  float scale = rsqrtf(tot * (1.f/1024.f) + 1e-6f);
  float4 wv = reinterpret_cast<const float4*>(w)[tid];
  float4 o;
  o.x = v.x*scale*wv.x; o.y = v.y*scale*wv.y;
  o.z = v.z*scale*wv.z; o.w = v.w*scale*wv.w;
  reinterpret_cast<float4*>(p)[tid] = o;
}

extern "C" void kernel_launch(void* const* d_in, const int* in_sizes, int n_in,
                              void* d_out, int out_size, void* d_ws, size_t ws_size,
                              hipStream_t stream) {
  const float* x      = (const float*)d_in[0];
  const float* w_key  = (const float*)d_in[1];
  const float* conv_w = (const float*)d_in[2];
  const float* conv_b = (const float*)d_in[3];
  const float* w1     = (const float*)d_in[4];
  const float* b1     = (const float*)d_in[5];
  const float* w2     = (const float*)d_in[6];
  const float* b2     = (const float*)d_in[7];
  const float* norm_w = (const float*)d_in[8];
  float* out = (float*)d_out;
  char*  ws  = (char*)d_ws;

  // workspace layout (~249 MB)
  size_t off = 0;
  float* RES  = (float*)(ws + off); off += (size_t)M_TOT*2048*4; // activated res; reused as hid
  float* HBUF = (float*)(ws + off); off += (size_t)M_TOT*1024*4; // h fp32
  u16*   XB   = (u16*)  (ws + off); off += (size_t)M_TOT*1024*2; // x bf16; reused as z
  u16*   WK   = (u16*)  (ws + off); off += (size_t)2048*1024*2;
  u16*   W1B  = (u16*)  (ws + off); off += (size_t)2048*1024*2;
  u16*   W2B  = (u16*)  (ws + off); off += (size_t)1024*2048*2;
  float* SA   = (float*)(ws + off); off += (size_t)BATCH*NCHUNK*1024*4;
  float* SB   = (float*)(ws + off); off += (size_t)BATCH*NCHUNK*1024*4;
  float* HP   = (float*)(ws + off); off += (size_t)BATCH*NCHUNK*1024*4;
  u16* ZB  = XB;        // z aliases x_bf16 (dead after GEMM1)
  u16* HID = (u16*)RES; // hid aliases res (dead after scan_stage3)

  // 1) fp32 -> bf16 converts
  cvt_bf16_k<<<(M_TOT*1024/4 + 255)/256, 256, 0, stream>>>(x,     XB,  M_TOT*1024/4);
  cvt_bf16_k<<<(2048*1024/4  + 255)/256, 256, 0, stream>>>(w_key, WK,  2048*1024/4);
  cvt_bf16_k<<<(2048*1024/4  + 255)/256, 256, 0, stream>>>(w1,    W1B, 2048*1024/4);
  cvt_bf16_k<<<(1024*2048/4  + 255)/256, 256, 0, stream>>>(w2,    W2B, 1024*2048/4);

  // 2) GEMM1 + activation epilogue -> res (fp32)
  gemm_bt<0><<<(M_TOT/128)*(2048/128), 256, 0, stream>>>(XB, WK, nullptr, RES, M_TOT, 2048, 1024);

  // 3) chunked scan -> h (fp32)
  scan_stage1<<<BATCH*NCHUNK*4, 256, 0, stream>>>(RES, SA, SB);
  scan_stage2<<<16, 256, 0, stream>>>(SA, SB, HP);
  scan_stage3<<<BATCH*NCHUNK*4, 256, 0, stream>>>(RES, HP, HBUF);

  // 4) depthwise conv + residual -> z (bf16)
  conv_z_k<<<(M_TOT*1024)/256, 256, 0, stream>>>(HBUF, conv_w, conv_b, ZB);

  // 5) GEMM2 + silu -> hid (bf16)
  gemm_bt<1><<<(M_TOT/128)*(2048/128), 256, 0, stream>>>(ZB, W1B, b1, HID, M_TOT, 2048, 1024);

  // 6) GEMM3 + bias -> out (fp32)
  gemm_bt<2><<<(M_TOT/128)*(1024/128), 256, 0, stream>>>(HID, W2B, b2, out, M_TOT, 1024, 2048);

  // 7) in-place RMSNorm
  rmsnorm_k<<<M_TOT, 256, 0, stream>>>(out, norm_w);
}

// Round 2
// 361.447 us; speedup vs baseline: 1.2303x; 1.2303x over previous
//
#include <hip/hip_runtime.h>

typedef unsigned short u16;
typedef unsigned int u32;
typedef __attribute__((ext_vector_type(8))) short short8;  // 8 bf16 = 4 VGPR (MFMA A/B frag)
typedef __attribute__((ext_vector_type(4))) float f32x4;   // MFMA C/D frag

#define T_LEN 4096
#define BATCH 4
#define M_TOT (BATCH*T_LEN)   /* 16384 rows */
#define NCHUNK 32
#define CLEN 128              /* 4096/32 */

__device__ __forceinline__ u16 f2bf(float f){
  u32 u = __builtin_bit_cast(u32, f);
  u32 r = (u + 0x7FFFu + ((u >> 16) & 1u)) >> 16;   // RTN-even
  return (u16)r;
}
__device__ __forceinline__ float sigmoid_(float v){ return 1.f/(1.f + __expf(-v)); }
// pi * tanh(v) = pi * (1 - 2/(exp(2v)+1)); robust at +-inf via expf saturation
__device__ __forceinline__ float tanh_pi_(float v){
  return 3.14159265358979323846f * (1.f - 2.f/(1.f + __expf(2.f*v)));
}

// ---------------- fp32 -> bf16 convert (vectorized x4) ----------------
__global__ __launch_bounds__(256) void cvt_bf16_k(const float* __restrict__ in,
                                                  u16* __restrict__ out, int n4){
  int g = blockIdx.x*256 + threadIdx.x;
  if (g >= n4) return;
  float4 v = reinterpret_cast<const float4*>(in)[g];
  reinterpret_cast<ushort4*>(out)[g] =
      make_ushort4(f2bf(v.x), f2bf(v.y), f2bf(v.z), f2bf(v.w));
}

// =================== 256x256 8-phase bf16 GEMM (T1+T2+T3+T4+T5) ===================
// C[M,N] = A[M,K] @ B[N,K]^T. 512 thr = 8 waves (2M x 4N), BK=64, LDS 128 KiB dyn.
// Staging unit "quarter" = 64 rows x 64 cols = 8 KB = 1 global_load_lds x16B/thread.
// Per-phase: 4 (or +8 at q0) ds_read_b128 | 2 stage issues | bar | lgkm0 | 16 MFMA | bar.
// vmcnt(6) only at phases 4/8 (3 half-tiles in flight); peeled last iter drains 0.
// LDS swizzle: byte ^= (row&7)<<4 on reads; inverse-swizzled GLOBAL src on stages
// (global_load_lds dest must stay linear — rule #21).

#define GBAR() do { __builtin_amdgcn_sched_barrier(0); __builtin_amdgcn_s_barrier(); \
                    __builtin_amdgcn_sched_barrier(0); } while(0)
#define WAITLGKM0() do { asm volatile("s_waitcnt lgkmcnt(0)" ::: "memory"); \
                         __builtin_amdgcn_sched_barrier(0); } while(0)
#define VMCNT(n) do { asm volatile("s_waitcnt vmcnt(" #n ")" ::: "memory"); \
                      __builtin_amdgcn_sched_barrier(0); } while(0)

#define STAGE(buf, ab, q, kt) do { \
  const u16* _s = ((ab) ? Bb : Ab) + (size_t)(q)*rowK64 + (size_t)(kt)*64; \
  __builtin_amdgcn_global_load_lds( \
    (const __attribute__((address_space(1))) void*)_s, \
    (__attribute__((address_space(3))) void*)(smem + (buf)*65536 + (ab)*32768 + (q)*8192 + stb), \
    16, 0, 0); \
} while(0)

#define LDA(buf, m, kk) (*(const short8*)(smem + (buf)*65536 + aRow + (m)*2048 + ((kk) ? csw1 : csw0)))
#define LDB(buf, n, kk) (*(const short8*)(smem + (buf)*65536 + 32768 + bRow + (n)*2048 + ((kk) ? csw1 : csw0)))

#define LOADB(buf) do { _Pragma("unroll") for (int n=0;n<4;n++){ \
    bfr0[n] = LDB(buf,n,0); bfr1[n] = LDB(buf,n,1); } } while(0)

#define PHASE_Q(buf, q, STMTS, ENDSTMT) do { \
  short8 _a00 = LDA(buf, 2*(q)  , 0); \
  short8 _a01 = LDA(buf, 2*(q)  , 1); \
  short8 _a10 = LDA(buf, 2*(q)+1, 0); \
  short8 _a11 = LDA(buf, 2*(q)+1, 1); \
  STMTS \
  GBAR(); \
  WAITLGKM0(); \
  __builtin_amdgcn_s_setprio(1); \
  _Pragma("unroll") \
  for (int n=0;n<4;n++){ \
    acc[2*(q)][n]   = __builtin_amdgcn_mfma_f32_16x16x32_bf16(_a00, bfr0[n], acc[2*(q)][n], 0,0,0); \
    acc[2*(q)][n]   = __builtin_amdgcn_mfma_f32_16x16x32_bf16(_a01, bfr1[n], acc[2*(q)][n], 0,0,0); \
    acc[2*(q)+1][n] = __builtin_amdgcn_mfma_f32_16x16x32_bf16(_a10, bfr0[n], acc[2*(q)+1][n], 0,0,0); \
    acc[2*(q)+1][n] = __builtin_amdgcn_mfma_f32_16x16x32_bf16(_a11, bfr1[n], acc[2*(q)+1][n], 0,0,0); \
  } \
  __builtin_amdgcn_s_setprio(0); \
  ENDSTMT \
  GBAR(); \
} while(0)

// EPI 0: GEMM1 -> fp32 activated res (col<1024: pi*tanh, else sigmoid)
// EPI 1: GEMM2 -> bf16 silu(v + bias)
// EPI 2: GEMM3 -> fp32 v + bias
template<int EPI>
__global__ __launch_bounds__(512, 2) void gemm8p(
    const u16* __restrict__ Ag, const u16* __restrict__ Bg,
    const float* __restrict__ bias, void* __restrict__ Cout,
    int M, int N, int K)
{
  extern __shared__ __attribute__((aligned(16))) char smem[];
  const int tid = threadIdx.x;
  const int wid = tid >> 6, lane = tid & 63;
  const int wr = wid >> 2, wc = wid & 3;        // wave -> 128x64 output subtile
  const int fr = lane & 15, fq = lane >> 4;

  // T1: bijective XCD swizzle (nwg % 8 == 0 for all our launches)
  const int nbn = N >> 8;
  const int nwg = gridDim.x;
  const int bid = blockIdx.x;
  const int swzb = (bid & 7) * (nwg >> 3) + (bid >> 3);
  const int bm = swzb / nbn, bn = swzb - bm * nbn;

  const size_t rowK64 = (size_t)64 * K;
  // staging: thread t covers LDS bytes qbase + t*16 (linear); global source is
  // inverse-swizzled: row = t>>3 (within quarter), chunk = (t&7) ^ ((t>>3)&7)
  const u16* Ab = Ag + ((size_t)bm*256 + (tid>>3)) * K + ((tid & 7) ^ ((tid >> 3) & 7)) * 8;
  const u16* Bb = Bg + ((size_t)bn*256 + (tid>>3)) * K + ((tid & 7) ^ ((tid >> 3) & 7)) * 8;
  const u32 stb = (u32)(wid << 10);   // wave-uniform LDS staging base within quarter

  // swizzled ds_read addressing (row&7 == fr&7 since m*16 = 0 mod 8)
  const u32 aRow = (u32)(wr*128 + fr) * 128;
  const u32 bRow = (u32)(wc*64  + fr) * 128;
  const u32 csw0 = (u32)((fq*16)      ^ ((fr & 7) << 4));
  const u32 csw1 = (u32)((64 + fq*16) ^ ((fr & 7) << 4));

  f32x4 acc[8][4];
#pragma unroll
  for (int m=0;m<8;m++)
#pragma unroll
    for (int n=0;n<4;n++) acc[m][n] = f32x4{0.f,0.f,0.f,0.f};

  short8 bfr0[4], bfr1[4];

  const int NT = K >> 6;   // K-tiles (16 or 32)

  // prologue: tile0 complete (8 loads), tile1 B + A-q0/q2 (6 loads), drain tile0
  STAGE(0,1,0,0); STAGE(0,1,1,0); STAGE(0,1,2,0); STAGE(0,1,3,0);
  STAGE(0,0,0,0); STAGE(0,0,1,0); STAGE(0,0,2,0); STAGE(0,0,3,0);
  STAGE(1,1,0,1); STAGE(1,1,1,1); STAGE(1,1,2,1); STAGE(1,1,3,1);
  STAGE(1,0,0,1); STAGE(1,0,2,1);
  VMCNT(6);
  GBAR();

  for (int i = 0; i < (NT>>1) - 1; ++i){
    const int tt = 2*i;
    // P0-P3: tile tt (buf0)
    PHASE_Q(0, 0, LOADB(0); STAGE(1,0,1,tt+1); STAGE(1,0,3,tt+1);, );
    PHASE_Q(0, 1, STAGE(0,1,0,tt+2); STAGE(0,1,1,tt+2);, );
    PHASE_Q(0, 2, STAGE(0,1,2,tt+2); STAGE(0,1,3,tt+2);, );
    PHASE_Q(0, 3, STAGE(0,0,0,tt+2); STAGE(0,0,2,tt+2);, VMCNT(6); );
    // P4-P7: tile tt+1 (buf1)
    PHASE_Q(1, 0, LOADB(1); STAGE(0,0,1,tt+2); STAGE(0,0,3,tt+2);, );
    PHASE_Q(1, 1, STAGE(1,1,0,tt+3); STAGE(1,1,1,tt+3);, );
    PHASE_Q(1, 2, STAGE(1,1,2,tt+3); STAGE(1,1,3,tt+3);, );
    PHASE_Q(1, 3, STAGE(1,0,0,tt+3); STAGE(1,0,2,tt+3);, VMCNT(6); );
  }
  { // peeled final iteration: tiles NT-2, NT-1; no new prefetch beyond K
    const int tt = NT-2;
    PHASE_Q(0, 0, LOADB(0); STAGE(1,0,1,tt+1); STAGE(1,0,3,tt+1);, );
    PHASE_Q(0, 1, , );
    PHASE_Q(0, 2, , );
    PHASE_Q(0, 3, , VMCNT(0); );
    PHASE_Q(1, 0, LOADB(1);, );
    PHASE_Q(1, 1, , );
    PHASE_Q(1, 2, , );
    PHASE_Q(1, 3, , );
  }

  // epilogue: D reg r -> row = fq*4 + r, col = fr (m89-verified mapping)
  const int orow0 = bm*256 + wr*128;
  const int ocol0 = bn*256 + wc*64;
#pragma unroll
  for (int m=0;m<8;m++){
#pragma unroll
    for (int n=0;n<4;n++){
      const int col = ocol0 + n*16 + fr;
#pragma unroll
      for (int r=0;r<4;r++){
        const int row = orow0 + m*16 + fq*4 + r;
        float v = acc[m][n][r];
        if constexpr (EPI == 0){
          float o = (col < 1024) ? tanh_pi_(v) : sigmoid_(v);
          ((float*)Cout)[(size_t)row*N + col] = o;
        } else if constexpr (EPI == 1){
          v += bias[col];
          ((u16*)Cout)[(size_t)row*N + col] = f2bf(v * sigmoid_(v));
        } else {
          v += bias[col];
          ((float*)Cout)[(size_t)row*N + col] = v;
        }
      }
    }
  }
}

// ---------------- chunked lerp scan ----------------
// res layout: [b][t][2048], col<1024 = theta' (pi*tanh), col>=1024 = s (sigmoid)
// recurrence: h_t = (1-s_t) h_{t-1} + s_t * theta'_t, h_{-1} = 0
__global__ __launch_bounds__(256) void scan_stage1(const float* __restrict__ res,
                                                   float* __restrict__ sA,
                                                   float* __restrict__ sB){
  const int c     = (blockIdx.x & 3)*256 + threadIdx.x;
  const int chunk = (blockIdx.x >> 2) & (NCHUNK-1);
  const int b     = blockIdx.x >> 7;
  const float* p = res + ((size_t)(b*T_LEN + chunk*CLEN))*2048 + c;
  float A = 1.f, Bv = 0.f;
#pragma unroll 4
  for (int t=0;t<CLEN;++t){
    float th = p[0];
    float s  = p[1024];
    float a  = 1.f - s;
    A  *= a;
    Bv  = a*Bv + s*th;
    p  += 2048;
  }
  const int idx = (b*NCHUNK + chunk)*1024 + c;
  sA[idx] = A; sB[idx] = Bv;
}

__global__ __launch_bounds__(256) void scan_stage2(const float* __restrict__ sA,
                                                   const float* __restrict__ sB,
                                                   float* __restrict__ Hp){
  const int g = blockIdx.x*256 + threadIdx.x;   // 4096 threads: b*1024+c
  const int b = g >> 10, c = g & 1023;
  float H = 0.f;
#pragma unroll
  for (int i=0;i<NCHUNK;++i){
    const int idx = (b*NCHUNK + i)*1024 + c;
    Hp[idx] = H;                 // state BEFORE chunk i
    H = sA[idx]*H + sB[idx];
  }
}

__global__ __launch_bounds__(256) void scan_stage3(const float* __restrict__ res,
                                                   const float* __restrict__ Hp,
                                                   float* __restrict__ h){
  const int c     = (blockIdx.x & 3)*256 + threadIdx.x;
  const int chunk = (blockIdx.x >> 2) & (NCHUNK-1);
  const int b     = blockIdx.x >> 7;
  const float* p = res + ((size_t)(b*T_LEN + chunk*CLEN))*2048 + c;
  float*       q = h   + ((size_t)(b*T_LEN + chunk*CLEN))*1024 + c;
  float H = Hp[(b*NCHUNK + chunk)*1024 + c];
#pragma unroll 4
  for (int t=0;t<CLEN;++t){
    float th = p[0];
    float s  = p[1024];
    H = (1.f - s)*H + s*th;
    q[0] = H;
    p += 2048; q += 1024;
  }
}

// ---------------- depthwise causal conv(3) + residual -> bf16 z ----------------
// conv[t] = h[t-2]*w0 + h[t-1]*w1 + h[t]*w2 ; z = h + conv + conv_b
__global__ __launch_bounds__(256) void conv_z_k(const float* __restrict__ h,
                                                const float* __restrict__ cw,
                                                const float* __restrict__ cb,
                                                u16* __restrict__ z){
  const int g = blockIdx.x*256 + threadIdx.x;
  const int c = g & 1023;
  const int t = (g >> 10) & (T_LEN-1);
  float h0  = h[g];
  float hm1 = (t >= 1) ? h[g-1024] : 0.f;
  float hm2 = (t >= 2) ? h[g-2048] : 0.f;
  float v = h0 + cb[c] + hm2*cw[3*c] + hm1*cw[3*c+1] + h0*cw[3*c+2];
  z[g] = f2bf(v);
}

// ---------------- in-place row RMSNorm (d=1024, one block per row) ----------------
__global__ __launch_bounds__(256) void rmsnorm_k(float* __restrict__ io,
                                                 const float* __restrict__ w){
  const int row = blockIdx.x;
  const int tid = threadIdx.x;
  float* p = io + (size_t)row*1024;
  float4 v = reinterpret_cast<const float4*>(p)[tid];
  float ss = v.x*v.x + v.y*v.y + v.z*v.z + v.w*v.w;
#pragma unroll
  for (int o=32; o>0; o>>=1) ss += __shfl_xor(ss, o, 64);
  __shared__ float red[4];
  if ((tid & 63) == 0) red[tid >> 6] = ss;
  __syncthreads();
  float tot = red[0] + red[1] + red[2] + red[3];
  float scale = rsqrtf(tot * (1.f/1024.f) + 1e-6f);
  float4 wv = reinterpret_cast<const float4*>(w)[tid];
  float4 o;
  o.x = v.x*scale*wv.x; o.y = v.y*scale*wv.y;
  o.z = v.z*scale*wv.z; o.w = v.w*scale*wv.w;
  reinterpret_cast<float4*>(p)[tid] = o;
}

extern "C" void kernel_launch(void* const* d_in, const int* in_sizes, int n_in,
                              void* d_out, int out_size, void* d_ws, size_t ws_size,
                              hipStream_t stream) {
  const float* x      = (const float*)d_in[0];
  const float* w_key  = (const float*)d_in[1];
  const float* conv_w = (const float*)d_in[2];
  const float* conv_b = (const float*)d_in[3];
  const float* w1     = (const float*)d_in[4];
  const float* b1     = (const float*)d_in[5];
  const float* w2     = (const float*)d_in[6];
  const float* b2     = (const float*)d_in[7];
  const float* norm_w = (const float*)d_in[8];
  float* out = (float*)d_out;
  char*  ws  = (char*)d_ws;

  // workspace layout (~249 MB)
  size_t off = 0;
  float* RES  = (float*)(ws + off); off += (size_t)M_TOT*2048*4; // activated res; reused as hid
  float* HBUF = (float*)(ws + off); off += (size_t)M_TOT*1024*4; // h fp32
  u16*   XB   = (u16*)  (ws + off); off += (size_t)M_TOT*1024*2; // x bf16; reused as z
  u16*   WK   = (u16*)  (ws + off); off += (size_t)2048*1024*2;
  u16*   W1B  = (u16*)  (ws + off); off += (size_t)2048*1024*2;
  u16*   W2B  = (u16*)  (ws + off); off += (size_t)1024*2048*2;
  float* SA   = (float*)(ws + off); off += (size_t)BATCH*NCHUNK*1024*4;
  float* SB   = (float*)(ws + off); off += (size_t)BATCH*NCHUNK*1024*4;
  float* HP   = (float*)(ws + off); off += (size_t)BATCH*NCHUNK*1024*4;
  u16* ZB  = XB;        // z aliases x_bf16 (dead after GEMM1)
  u16* HID = (u16*)RES; // hid aliases res (dead after scan_stage3)

  // allow 128 KiB dynamic LDS (idempotent host-side calls, graph-capture safe)
  hipFuncSetAttribute((const void*)gemm8p<0>, hipFuncAttributeMaxDynamicSharedMemorySize, 131072);
  hipFuncSetAttribute((const void*)gemm8p<1>, hipFuncAttributeMaxDynamicSharedMemorySize, 131072);
  hipFuncSetAttribute((const void*)gemm8p<2>, hipFuncAttributeMaxDynamicSharedMemorySize, 131072);

  // 1) fp32 -> bf16 converts
  cvt_bf16_k<<<(M_TOT*1024/4 + 255)/256, 256, 0, stream>>>(x,     XB,  M_TOT*1024/4);
  cvt_bf16_k<<<(2048*1024/4  + 255)/256, 256, 0, stream>>>(w_key, WK,  2048*1024/4);
  cvt_bf16_k<<<(2048*1024/4  + 255)/256, 256, 0, stream>>>(w1,    W1B, 2048*1024/4);
  cvt_bf16_k<<<(1024*2048/4  + 255)/256, 256, 0, stream>>>(w2,    W2B, 1024*2048/4);

  // 2) GEMM1 + activation epilogue -> res (fp32)
  gemm8p<0><<<(M_TOT/256)*(2048/256), 512, 131072, stream>>>(XB, WK, nullptr, RES, M_TOT, 2048, 1024);

  // 3) chunked scan -> h (fp32)
  scan_stage1<<<BATCH*NCHUNK*4, 256, 0, stream>>>(RES, SA, SB);
  scan_stage2<<<16, 256, 0, stream>>>(SA, SB, HP);
  scan_stage3<<<BATCH*NCHUNK*4, 256, 0, stream>>>(RES, HP, HBUF);

  // 4) depthwise conv + residual -> z (bf16)
  conv_z_k<<<(M_TOT*1024)/256, 256, 0, stream>>>(HBUF, conv_w, conv_b, ZB);

  // 5) GEMM2 + silu -> hid (bf16)
  gemm8p<1><<<(M_TOT/256)*(2048/256), 512, 131072, stream>>>(ZB, W1B, b1, HID, M_TOT, 2048, 1024);

  // 6) GEMM3 + bias -> out (fp32)
  gemm8p<2><<<(M_TOT/256)*(1024/256), 512, 131072, stream>>>(HID, W2B, b2, out, M_TOT, 1024, 2048);

  // 7) in-place RMSNorm
  rmsnorm_k<<<M_TOT, 256, 0, stream>>>(out, norm_w);
}

// Round 3
// 328.815 us; speedup vs baseline: 1.3524x; 1.0992x over previous
//
#include <hip/hip_runtime.h>

typedef unsigned short u16;
typedef unsigned int u32;
typedef __attribute__((ext_vector_type(8))) short short8;  // 8 bf16 = 4 VGPR (MFMA A/B frag)
typedef __attribute__((ext_vector_type(4))) float f32x4;   // MFMA C/D frag

#define T_LEN 4096
#define BATCH 4
#define M_TOT (BATCH*T_LEN)   /* 16384 rows */
#define NCHUNK 32
#define CLEN 128              /* 4096/32 */

__device__ __forceinline__ u16 f2bf(float f){
  u32 u = __builtin_bit_cast(u32, f);
  u32 r = (u + 0x7FFFu + ((u >> 16) & 1u)) >> 16;   // RTN-even
  return (u16)r;
}
__device__ __forceinline__ float sigmoid_(float v){ return 1.f/(1.f + __expf(-v)); }
// pi * tanh(v) = pi * (1 - 2/(exp(2v)+1)); robust at +-inf via expf saturation
__device__ __forceinline__ float tanh_pi_(float v){
  return 3.14159265358979323846f * (1.f - 2.f/(1.f + __expf(2.f*v)));
}

// ---------------- fp32 -> bf16 convert (vectorized x4) ----------------
__global__ __launch_bounds__(256) void cvt_bf16_k(const float* __restrict__ in,
                                                  u16* __restrict__ out, int n4){
  int g = blockIdx.x*256 + threadIdx.x;
  if (g >= n4) return;
  float4 v = reinterpret_cast<const float4*>(in)[g];
  reinterpret_cast<ushort4*>(out)[g] =
      make_ushort4(f2bf(v.x), f2bf(v.y), f2bf(v.z), f2bf(v.w));
}

// =================== 256x256 8-phase bf16 GEMM (T1+T2+T3+T4+T5) ===================
// C[M,N] = A[M,K] @ B[N,K]^T. 512 thr = 8 waves (2M x 4N), BK=64, LDS 128 KiB dyn.
// Staging unit "quarter" = 64 rows x 64 cols = 8 KB = 1 global_load_lds x16B/thread.
// Per-phase: ds_reads | 2 stage issues | bar | lgkm0 | setprio(1) 16 MFMA | ENDSTMT | bar.
// vmcnt(6) only at phases 4/8 (3 half-tiles in flight); peeled last iter drains 0.
// NO sched_barrier fences (m141 lesson): plain s_barrier + bare waitcnt asm lets the
// compiler emit fine-grained lgkmcnt and interleave ds_read/addr-calc with MFMA.
// Hoist safety: reads crossing a plain barrier upward only reach buffers already
// valid; the hazardous boundaries (phase 4/8 ends) carry the vmcnt asm with memory
// clobber which memory ops cannot cross.
// LDS swizzle: byte ^= (row&7)<<4 on reads; inverse-swizzled GLOBAL src on stages
// (global_load_lds dest must stay linear — rule #21).

#define BAR() __builtin_amdgcn_s_barrier()
#define WAITLGKM0() asm volatile("s_waitcnt lgkmcnt(0)" ::: "memory")
#define VMCNT(n) asm volatile("s_waitcnt vmcnt(" #n ")" ::: "memory")

#define STAGE(buf, ab, q, kt) do { \
  const u16* _s = ((ab) ? Bb : Ab) + (size_t)(q)*rowK64 + (size_t)(kt)*64; \
  __builtin_amdgcn_global_load_lds( \
    (const __attribute__((address_space(1))) void*)_s, \
    (__attribute__((address_space(3))) void*)(smem + (buf)*65536 + (ab)*32768 + (q)*8192 + stb), \
    16, 0, 0); \
} while(0)

#define LDA(buf, m, kk) (*(const short8*)(smem + (buf)*65536 + aRow + (m)*2048 + ((kk) ? csw1 : csw0)))
#define LDB(buf, n, kk) (*(const short8*)(smem + (buf)*65536 + 32768 + bRow + (n)*2048 + ((kk) ? csw1 : csw0)))

#define LOADB(buf) do { _Pragma("unroll") for (int n=0;n<4;n++){ \
    bfr0[n] = LDB(buf,n,0); bfr1[n] = LDB(buf,n,1); } } while(0)

#define PHASE_Q(buf, q, STMTS, ENDSTMT) do { \
  short8 _a00 = LDA(buf, 2*(q)  , 0); \
  short8 _a01 = LDA(buf, 2*(q)  , 1); \
  short8 _a10 = LDA(buf, 2*(q)+1, 0); \
  short8 _a11 = LDA(buf, 2*(q)+1, 1); \
  STMTS \
  BAR(); \
  WAITLGKM0(); \
  __builtin_amdgcn_s_setprio(1); \
  _Pragma("unroll") \
  for (int n=0;n<4;n++){ \
    acc[2*(q)][n]   = __builtin_amdgcn_mfma_f32_16x16x32_bf16(_a00, bfr0[n], acc[2*(q)][n], 0,0,0); \
    acc[2*(q)][n]   = __builtin_amdgcn_mfma_f32_16x16x32_bf16(_a01, bfr1[n], acc[2*(q)][n], 0,0,0); \
    acc[2*(q)+1][n] = __builtin_amdgcn_mfma_f32_16x16x32_bf16(_a10, bfr0[n], acc[2*(q)+1][n], 0,0,0); \
    acc[2*(q)+1][n] = __builtin_amdgcn_mfma_f32_16x16x32_bf16(_a11, bfr1[n], acc[2*(q)+1][n], 0,0,0); \
  } \
  __builtin_amdgcn_s_setprio(0); \
  ENDSTMT \
  BAR(); \
} while(0)

// EPI 0: GEMM1 -> fp32 activated res (col<1024: pi*tanh, else sigmoid)
// EPI 1: GEMM2 -> bf16 silu(v + bias)
// EPI 2: GEMM3 -> fp32 v + bias
template<int EPI>
__global__ __launch_bounds__(512, 2) void gemm8p(
    const u16* __restrict__ Ag, const u16* __restrict__ Bg,
    const float* __restrict__ bias, void* __restrict__ Cout,
    int M, int N, int K)
{
  extern __shared__ __attribute__((aligned(16))) char smem[];
  const int tid = threadIdx.x;
  const int wid = tid >> 6, lane = tid & 63;
  const int wr = wid >> 2, wc = wid & 3;        // wave -> 128x64 output subtile
  const int fr = lane & 15, fq = lane >> 4;

  // T1: bijective XCD swizzle (nwg % 8 == 0 for all our launches)
  const int nbn = N >> 8;
  const int nwg = gridDim.x;
  const int bid = blockIdx.x;
  const int swzb = (bid & 7) * (nwg >> 3) + (bid >> 3);
  const int bm = swzb / nbn, bn = swzb - bm * nbn;

  const size_t rowK64 = (size_t)64 * K;
  // staging: thread t covers LDS bytes qbase + t*16 (linear); global source is
  // inverse-swizzled: row = t>>3 (within quarter), chunk = (t&7) ^ ((t>>3)&7)
  const u16* Ab = Ag + ((size_t)bm*256 + (tid>>3)) * K + ((tid & 7) ^ ((tid >> 3) & 7)) * 8;
  const u16* Bb = Bg + ((size_t)bn*256 + (tid>>3)) * K + ((tid & 7) ^ ((tid >> 3) & 7)) * 8;
  const u32 stb = (u32)(wid << 10);   // wave-uniform LDS staging base within quarter

  // swizzled ds_read addressing (row&7 == fr&7 since m*16 = 0 mod 8)
  const u32 aRow = (u32)(wr*128 + fr) * 128;
  const u32 bRow = (u32)(wc*64  + fr) * 128;
  const u32 csw0 = (u32)((fq*16)      ^ ((fr & 7) << 4));
  const u32 csw1 = (u32)((64 + fq*16) ^ ((fr & 7) << 4));

  f32x4 acc[8][4];
#pragma unroll
  for (int m=0;m<8;m++)
#pragma unroll
    for (int n=0;n<4;n++) acc[m][n] = f32x4{0.f,0.f,0.f,0.f};

  short8 bfr0[4], bfr1[4];

  const int NT = K >> 6;   // K-tiles (16 or 32)

  // prologue: tile0 complete (8 loads), tile1 B + A-q0/q2 (6 loads), drain tile0
  STAGE(0,1,0,0); STAGE(0,1,1,0); STAGE(0,1,2,0); STAGE(0,1,3,0);
  STAGE(0,0,0,0); STAGE(0,0,1,0); STAGE(0,0,2,0); STAGE(0,0,3,0);
  STAGE(1,1,0,1); STAGE(1,1,1,1); STAGE(1,1,2,1); STAGE(1,1,3,1);
  STAGE(1,0,0,1); STAGE(1,0,2,1);
  VMCNT(6);
  BAR();

  for (int i = 0; i < (NT>>1) - 1; ++i){
    const int tt = 2*i;
    // P0-P3: tile tt (buf0)
    PHASE_Q(0, 0, LOADB(0); STAGE(1,0,1,tt+1); STAGE(1,0,3,tt+1);, );
    PHASE_Q(0, 1, STAGE(0,1,0,tt+2); STAGE(0,1,1,tt+2);, );
    PHASE_Q(0, 2, STAGE(0,1,2,tt+2); STAGE(0,1,3,tt+2);, );
    PHASE_Q(0, 3, STAGE(0,0,0,tt+2); STAGE(0,0,2,tt+2);, VMCNT(6); );
    // P4-P7: tile tt+1 (buf1)
    PHASE_Q(1, 0, LOADB(1); STAGE(0,0,1,tt+2); STAGE(0,0,3,tt+2);, );
    PHASE_Q(1, 1, STAGE(1,1,0,tt+3); STAGE(1,1,1,tt+3);, );
    PHASE_Q(1, 2, STAGE(1,1,2,tt+3); STAGE(1,1,3,tt+3);, );
    PHASE_Q(1, 3, STAGE(1,0,0,tt+3); STAGE(1,0,2,tt+3);, VMCNT(6); );
  }
  { // peeled final iteration: tiles NT-2, NT-1; no new prefetch beyond K
    const int tt = NT-2;
    PHASE_Q(0, 0, LOADB(0); STAGE(1,0,1,tt+1); STAGE(1,0,3,tt+1);, );
    PHASE_Q(0, 1, , );
    PHASE_Q(0, 2, , );
    PHASE_Q(0, 3, , VMCNT(0); );
    PHASE_Q(1, 0, LOADB(1);, );
    PHASE_Q(1, 1, , );
    PHASE_Q(1, 2, , );
    PHASE_Q(1, 3, , );
  }

  // epilogue: D reg r -> row = fq*4 + r, col = fr (m89-verified mapping)
  const int orow0 = bm*256 + wr*128;
  const int ocol0 = bn*256 + wc*64;
#pragma unroll
  for (int m=0;m<8;m++){
#pragma unroll
    for (int n=0;n<4;n++){
      const int col = ocol0 + n*16 + fr;
#pragma unroll
      for (int r=0;r<4;r++){
        const int row = orow0 + m*16 + fq*4 + r;
        float v = acc[m][n][r];
        if constexpr (EPI == 0){
          float o = (col < 1024) ? tanh_pi_(v) : sigmoid_(v);
          ((float*)Cout)[(size_t)row*N + col] = o;
        } else if constexpr (EPI == 1){
          v += bias[col];
          ((u16*)Cout)[(size_t)row*N + col] = f2bf(v * sigmoid_(v));
        } else {
          v += bias[col];
          ((float*)Cout)[(size_t)row*N + col] = v;
        }
      }
    }
  }
}

// ---------------- chunked lerp scan ----------------
// res layout: [b][t][2048], col<1024 = theta' (pi*tanh), col>=1024 = s (sigmoid)
// recurrence: h_t = (1-s_t) h_{t-1} + s_t * theta'_t, h_{-1} = 0
// stage1 outputs full-chunk products (A,B) AND products excluding the last
// timestep (A2,B2) so the fused stage3+conv can reconstruct h[t0-2].
__global__ __launch_bounds__(256) void scan_stage1(const float* __restrict__ res,
                                                   float* __restrict__ sA,
                                                   float* __restrict__ sB,
                                                   float* __restrict__ sA2,
                                                   float* __restrict__ sB2){
  const int c     = (blockIdx.x & 3)*256 + threadIdx.x;
  const int chunk = (blockIdx.x >> 2) & (NCHUNK-1);
  const int b     = blockIdx.x >> 7;
  const float* p = res + ((size_t)(b*T_LEN + chunk*CLEN))*2048 + c;
  float A = 1.f, Bv = 0.f;
#pragma unroll 4
  for (int t=0;t<CLEN-1;++t){
    float th = p[0];
    float s  = p[1024];
    float a  = 1.f - s;
    A  *= a;
    Bv  = a*Bv + s*th;
    p  += 2048;
  }
  const int idx = (b*NCHUNK + chunk)*1024 + c;
  sA2[idx] = A; sB2[idx] = Bv;         // state transform through t0..t0+126
  {
    float th = p[0];
    float s  = p[1024];
    float a  = 1.f - s;
    A  *= a;
    Bv  = a*Bv + s*th;
  }
  sA[idx] = A; sB[idx] = Bv;
}

__global__ __launch_bounds__(256) void scan_stage2(const float* __restrict__ sA,
                                                   const float* __restrict__ sB,
                                                   float* __restrict__ Hp){
  const int g = blockIdx.x*256 + threadIdx.x;   // 4096 threads: b*1024+c
  const int b = g >> 10, c = g & 1023;
  float H = 0.f;
#pragma unroll
  for (int i=0;i<NCHUNK;++i){
    const int idx = (b*NCHUNK + i)*1024 + c;
    Hp[idx] = H;                 // state BEFORE chunk i
    H = sA[idx]*H + sB[idx];
  }
}

// ---------------- fused stage3 + depthwise causal conv(3) -> bf16 z ----------------
// h_t recomputed sequentially; conv[t] = h[t-2]*w0 + h[t-1]*w1 + h[t]*w2;
// z = h + conv + conv_b, written directly as bf16. Chunk-boundary history:
// h[t0-1] = Hp[c]; h[t0-2] = A2[c-1]*Hp[c-1] + B2[c-1] (zero for chunk 0).
__global__ __launch_bounds__(256) void scan3_conv_k(const float* __restrict__ res,
                                                    const float* __restrict__ Hp,
                                                    const float* __restrict__ sA2,
                                                    const float* __restrict__ sB2,
                                                    const float* __restrict__ cw,
                                                    const float* __restrict__ cb,
                                                    u16* __restrict__ z){
  const int c     = (blockIdx.x & 3)*256 + threadIdx.x;
  const int chunk = (blockIdx.x >> 2) & (NCHUNK-1);
  const int b     = blockIdx.x >> 7;
  const float* p = res + ((size_t)(b*T_LEN + chunk*CLEN))*2048 + c;
  u16*         q = z   + ((size_t)(b*T_LEN + chunk*CLEN))*1024 + c;
  const int idx = (b*NCHUNK + chunk)*1024 + c;
  float H   = Hp[idx];           // = h[t0-1] (0 for chunk 0)
  float hm1 = H;
  float hm2 = 0.f;
  if (chunk > 0){
    const int pidx = idx - 1024;
    hm2 = sA2[pidx]*Hp[pidx] + sB2[pidx];   // = h[t0-2]
  }
  const float w0 = cw[3*c], w1 = cw[3*c+1], w2 = cw[3*c+2], bb = cb[c];
#pragma unroll 4
  for (int t=0;t<CLEN;++t){
    float th = p[0];
    float s  = p[1024];
    H = (1.f - s)*H + s*th;
    float v = H + bb + hm2*w0 + hm1*w1 + H*w2;
    q[0] = f2bf(v);
    hm2 = hm1; hm1 = H;
    p += 2048; q += 1024;
  }
}

// ---------------- in-place row RMSNorm (d=1024, one block per row) ----------------
__global__ __launch_bounds__(256) void rmsnorm_k(float* __restrict__ io,
                                                 const float* __restrict__ w){
  const int row = blockIdx.x;
  const int tid = threadIdx.x;
  float* p = io + (size_t)row*1024;
  float4 v = reinterpret_cast<const float4*>(p)[tid];
  float ss = v.x*v.x + v.y*v.y + v.z*v.z + v.w*v.w;
#pragma unroll
  for (int o=32; o>0; o>>=1) ss += __shfl_xor(ss, o, 64);
  __shared__ float red[4];
  if ((tid & 63) == 0) red[tid >> 6] = ss;
  __syncthreads();
  float tot = red[0] + red[1] + red[2] + red[3];
  float scale = rsqrtf(tot * (1.f/1024.f) + 1e-6f);
  float4 wv = reinterpret_cast<const float4*>(w)[tid];
  float4 o;
  o.x = v.x*scale*wv.x; o.y = v.y*scale*wv.y;
  o.z = v.z*scale*wv.z; o.w = v.w*scale*wv.w;
  reinterpret_cast<float4*>(p)[tid] = o;
}

extern "C" void kernel_launch(void* const* d_in, const int* in_sizes, int n_in,
                              void* d_out, int out_size, void* d_ws, size_t ws_size,
                              hipStream_t stream) {
  const float* x      = (const float*)d_in[0];
  const float* w_key  = (const float*)d_in[1];
  const float* conv_w = (const float*)d_in[2];
  const float* conv_b = (const float*)d_in[3];
  const float* w1     = (const float*)d_in[4];
  const float* b1     = (const float*)d_in[5];
  const float* w2     = (const float*)d_in[6];
  const float* b2     = (const float*)d_in[7];
  const float* norm_w = (const float*)d_in[8];
  float* out = (float*)d_out;
  char*  ws  = (char*)d_ws;

  // workspace layout (~185 MB)
  size_t off = 0;
  float* RES  = (float*)(ws + off); off += (size_t)M_TOT*2048*4; // activated res; reused as hid
  u16*   XB   = (u16*)  (ws + off); off += (size_t)M_TOT*1024*2; // x bf16; reused as z
  u16*   WK   = (u16*)  (ws + off); off += (size_t)2048*1024*2;
  u16*   W1B  = (u16*)  (ws + off); off += (size_t)2048*1024*2;
  u16*   W2B  = (u16*)  (ws + off); off += (size_t)1024*2048*2;
  float* SA   = (float*)(ws + off); off += (size_t)BATCH*NCHUNK*1024*4;
  float* SB   = (float*)(ws + off); off += (size_t)BATCH*NCHUNK*1024*4;
  float* SA2  = (float*)(ws + off); off += (size_t)BATCH*NCHUNK*1024*4;
  float* SB2  = (float*)(ws + off); off += (size_t)BATCH*NCHUNK*1024*4;
  float* HP   = (float*)(ws + off); off += (size_t)BATCH*NCHUNK*1024*4;
  u16* ZB  = XB;        // z aliases x_bf16 (dead after GEMM1)
  u16* HID = (u16*)RES; // hid aliases res (dead after scan3_conv_k)

  // allow 128 KiB dynamic LDS (idempotent host-side calls, graph-capture safe)
  hipFuncSetAttribute((const void*)gemm8p<0>, hipFuncAttributeMaxDynamicSharedMemorySize, 131072);
  hipFuncSetAttribute((const void*)gemm8p<1>, hipFuncAttributeMaxDynamicSharedMemorySize, 131072);
  hipFuncSetAttribute((const void*)gemm8p<2>, hipFuncAttributeMaxDynamicSharedMemorySize, 131072);

  // 1) fp32 -> bf16 converts
  cvt_bf16_k<<<(M_TOT*1024/4 + 255)/256, 256, 0, stream>>>(x,     XB,  M_TOT*1024/4);
  cvt_bf16_k<<<(2048*1024/4  + 255)/256, 256, 0, stream>>>(w_key, WK,  2048*1024/4);
  cvt_bf16_k<<<(2048*1024/4  + 255)/256, 256, 0, stream>>>(w1,    W1B, 2048*1024/4);
  cvt_bf16_k<<<(1024*2048/4  + 255)/256, 256, 0, stream>>>(w2,    W2B, 1024*2048/4);

  // 2) GEMM1 + activation epilogue -> res (fp32)
  gemm8p<0><<<(M_TOT/256)*(2048/256), 512, 131072, stream>>>(XB, WK, nullptr, RES, M_TOT, 2048, 1024);

  // 3) chunked scan; stage3 fused with depthwise conv -> z (bf16)
  scan_stage1<<<BATCH*NCHUNK*4, 256, 0, stream>>>(RES, SA, SB, SA2, SB2);
  scan_stage2<<<16, 256, 0, stream>>>(SA, SB, HP);
  scan3_conv_k<<<BATCH*NCHUNK*4, 256, 0, stream>>>(RES, HP, SA2, SB2, conv_w, conv_b, ZB);

  // 5) GEMM2 + silu -> hid (bf16)
  gemm8p<1><<<(M_TOT/256)*(2048/256), 512, 131072, stream>>>(ZB, W1B, b1, HID, M_TOT, 2048, 1024);

  // 6) GEMM3 + bias -> out (fp32)
  gemm8p<2><<<(M_TOT/256)*(1024/256), 512, 131072, stream>>>(HID, W2B, b2, out, M_TOT, 1024, 2048);

  // 7) in-place RMSNorm
  rmsnorm_k<<<M_TOT, 256, 0, stream>>>(out, norm_w);
}

// Round 4
// 316.844 us; speedup vs baseline: 1.4035x; 1.0378x over previous
//
#include <hip/hip_runtime.h>

typedef unsigned short u16;
typedef unsigned int u32;
typedef __attribute__((ext_vector_type(8))) short short8;  // 8 bf16 = 4 VGPR (MFMA A/B frag)
typedef __attribute__((ext_vector_type(4))) float f32x4;   // MFMA C/D frag

#define T_LEN 4096
#define BATCH 4
#define M_TOT (BATCH*T_LEN)   /* 16384 rows */
#define NCHUNK 32
#define CLEN 128              /* 4096/32 */

__device__ __forceinline__ u16 f2bf(float f){
  u32 u = __builtin_bit_cast(u32, f);
  u32 r = (u + 0x7FFFu + ((u >> 16) & 1u)) >> 16;   // RTN-even
  return (u16)r;
}
__device__ __forceinline__ float bf2f(u16 h){
  u32 u = ((u32)h) << 16; return __builtin_bit_cast(float, u);
}
__device__ __forceinline__ float sigmoid_(float v){ return 1.f/(1.f + __expf(-v)); }
__device__ __forceinline__ float tanh_pi_(float v){
  return 3.14159265358979323846f * (1.f - 2.f/(1.f + __expf(2.f*v)));
}

// ---------------- fp32 -> bf16 convert (vectorized x4) ----------------
__global__ __launch_bounds__(256) void cvt_bf16_k(const float* __restrict__ in,
                                                  u16* __restrict__ out, int n4){
  int g = blockIdx.x*256 + threadIdx.x;
  if (g >= n4) return;
  float4 v = reinterpret_cast<const float4*>(in)[g];
  reinterpret_cast<ushort4*>(out)[g] =
      make_ushort4(f2bf(v.x), f2bf(v.y), f2bf(v.z), f2bf(v.w));
}

// =================== 256x256 8-phase bf16 GEMM, read-pipelined ===================
// C[M,N] = A[M,K] @ B[N,K]^T. 512 thr = 8 waves (2M x 4N), BK=64, LDS 128 KiB dyn.
// KEY change vs r3: fragment ds_reads for phase p+1 are issued INSIDE phase p's
// MFMA window (after lgkm0, among MFMAs) with double-buffered frag regs, so the
// per-CU LDS-read time (~2300 cyc/K-tile) overlaps the MFMA time (~2500 cyc)
// instead of serializing with it. Cross-buffer prefetch at P3/P7 is made safe by
// moving VMCNT(6) to BEFORE the MFMA cluster: it retires exactly the 8 oldest
// loads = all quarters of the next tile. Read-vs-overwrite audit: every quarter
// read with lgkm-wait in phase p is re-staged no earlier than phase p+1 (one
// barrier after all readers' lgkm0).
#define BAR() __builtin_amdgcn_s_barrier()
#define WAITLGKM0() asm volatile("s_waitcnt lgkmcnt(0)" ::: "memory")
#define VMCNT(n) asm volatile("s_waitcnt vmcnt(" #n ")" ::: "memory")

#define STAGE(buf, ab, q, kt) do { \
  const u16* _s = ((ab) ? Bb : Ab) + (size_t)(q)*rowK64 + (size_t)(kt)*64; \
  __builtin_amdgcn_global_load_lds( \
    (const __attribute__((address_space(1))) void*)_s, \
    (__attribute__((address_space(3))) void*)(smem + (buf)*65536 + (ab)*32768 + (q)*8192 + stb), \
    16, 0, 0); \
} while(0)

#define LDA(buf, m, kk) (*(const short8*)(smem + (buf)*65536 + aRow + (m)*2048 + ((kk) ? csw1 : csw0)))
#define LDB(buf, n, kk) (*(const short8*)(smem + (buf)*65536 + 32768 + bRow + (n)*2048 + ((kk) ? csw1 : csw0)))

#define PFA(dst, buf, q) do { \
  dst[0] = LDA(buf, 2*(q),   0); \
  dst[1] = LDA(buf, 2*(q),   1); \
  dst[2] = LDA(buf, 2*(q)+1, 0); \
  dst[3] = LDA(buf, 2*(q)+1, 1); } while(0)

#define PFB(d0, d1, buf) do { _Pragma("unroll") \
  for (int n=0;n<4;n++){ d0[n] = LDB(buf,n,0); d1[n] = LDB(buf,n,1); } } while(0)

#define MFMA_Q(q, A, B0, B1) do { _Pragma("unroll") \
  for (int n=0;n<4;n++){ \
    acc[2*(q)][n]   = __builtin_amdgcn_mfma_f32_16x16x32_bf16(A[0], B0[n], acc[2*(q)][n], 0,0,0); \
    acc[2*(q)][n]   = __builtin_amdgcn_mfma_f32_16x16x32_bf16(A[1], B1[n], acc[2*(q)][n], 0,0,0); \
    acc[2*(q)+1][n] = __builtin_amdgcn_mfma_f32_16x16x32_bf16(A[2], B0[n], acc[2*(q)+1][n], 0,0,0); \
    acc[2*(q)+1][n] = __builtin_amdgcn_mfma_f32_16x16x32_bf16(A[3], B1[n], acc[2*(q)+1][n], 0,0,0); \
  } } while(0)

#define PRIO1() __builtin_amdgcn_s_setprio(1)
#define PRIO0() __builtin_amdgcn_s_setprio(0)

// EPI 0: GEMM1 -> bf16 activated res (col<1024: pi*tanh, else sigmoid)
// EPI 1: GEMM2 -> bf16 silu(v + bias)
// EPI 2: GEMM3 -> fp32 v + bias
template<int EPI>
__global__ __launch_bounds__(512, 2) void gemm8p(
    const u16* __restrict__ Ag, const u16* __restrict__ Bg,
    const float* __restrict__ bias, void* __restrict__ Cout,
    int M, int N, int K)
{
  extern __shared__ __attribute__((aligned(16))) char smem[];
  const int tid = threadIdx.x;
  const int wid = tid >> 6, lane = tid & 63;
  const int wr = wid >> 2, wc = wid & 3;        // wave -> 128x64 output subtile
  const int fr = lane & 15, fq = lane >> 4;

  // T1: bijective XCD swizzle (nwg % 8 == 0 for all our launches)
  const int nbn = N >> 8;
  const int nwg = gridDim.x;
  const int bid = blockIdx.x;
  const int swzb = (bid & 7) * (nwg >> 3) + (bid >> 3);
  const int bm = swzb / nbn, bn = swzb - bm * nbn;

  const size_t rowK64 = (size_t)64 * K;
  // staging: thread t covers LDS bytes qbase + t*16 (linear); global source is
  // inverse-swizzled: row = t>>3 (within quarter), chunk = (t&7) ^ ((t>>3)&7)
  const u16* Ab = Ag + ((size_t)bm*256 + (tid>>3)) * K + ((tid & 7) ^ ((tid >> 3) & 7)) * 8;
  const u16* Bb = Bg + ((size_t)bn*256 + (tid>>3)) * K + ((tid & 7) ^ ((tid >> 3) & 7)) * 8;
  const u32 stb = (u32)(wid << 10);   // wave-uniform LDS staging base within quarter

  // swizzled ds_read addressing (row&7 == fr&7 since m*16 = 0 mod 8)
  const u32 aRow = (u32)(wr*128 + fr) * 128;
  const u32 bRow = (u32)(wc*64  + fr) * 128;
  const u32 csw0 = (u32)((fq*16)      ^ ((fr & 7) << 4));
  const u32 csw1 = (u32)((64 + fq*16) ^ ((fr & 7) << 4));

  f32x4 acc[8][4];
#pragma unroll
  for (int m=0;m<8;m++)
#pragma unroll
    for (int n=0;n<4;n++) acc[m][n] = f32x4{0.f,0.f,0.f,0.f};

  short8 bP0[4], bP1[4], bN0[4], bN1[4];   // B frags: current tile / next tile
  short8 aP[4], aN[4];                     // A frags: alternating per phase

  const int NT = K >> 6;   // K-tiles (16 or 32)

  // prologue: tile0 -> buf0 (8 loads); tile1 -> buf1 B all + A q0,q2 (6 loads)
  STAGE(0,1,0,0); STAGE(0,1,1,0); STAGE(0,1,2,0); STAGE(0,1,3,0);
  STAGE(0,0,0,0); STAGE(0,0,1,0); STAGE(0,0,2,0); STAGE(0,0,3,0);
  STAGE(1,1,0,1); STAGE(1,1,1,1); STAGE(1,1,2,1); STAGE(1,1,3,1);
  STAGE(1,0,0,1); STAGE(1,0,2,1);
  VMCNT(6);           // tile0 fully landed; 6 in flight (tile1 partial)
  BAR();
  PFB(bP0, bP1, 0);   // pre-read tile0 B + A-q0; waited by loop P0's lgkm0
  PFA(aP, 0, 0);

  for (int i = 0; i < (NT>>1) - 1; ++i){
    const int tt = 2*i;
    // P0: MFMA buf0/q0 | pf A(buf0,p1)
    STAGE(1,0,1,tt+1); STAGE(1,0,3,tt+1);
    BAR(); WAITLGKM0();
    PRIO1(); MFMA_Q(0, aP, bP0, bP1); PFA(aN, 0, 1); PRIO0();
    BAR();
    // P1
    STAGE(0,1,0,tt+2); STAGE(0,1,1,tt+2);
    BAR(); WAITLGKM0();
    PRIO1(); MFMA_Q(1, aN, bP0, bP1); PFA(aP, 0, 2); PRIO0();
    BAR();
    // P2
    STAGE(0,1,2,tt+2); STAGE(0,1,3,tt+2);
    BAR(); WAITLGKM0();
    PRIO1(); MFMA_Q(2, aP, bP0, bP1); PFA(aN, 0, 3); PRIO0();
    BAR();
    // P3: vmcnt BEFORE MFMA retires prev-P5..P0 loads = all of tile tt+1
    STAGE(0,0,0,tt+2); STAGE(0,0,2,tt+2);
    BAR(); WAITLGKM0(); VMCNT(6);
    PRIO1(); MFMA_Q(3, aN, bP0, bP1); PFB(bN0, bN1, 1); PFA(aP, 1, 0); PRIO0();
    BAR();
    // P4: MFMA buf1/q0
    STAGE(0,0,1,tt+2); STAGE(0,0,3,tt+2);
    BAR(); WAITLGKM0();
    PRIO1(); MFMA_Q(0, aP, bN0, bN1); PFA(aN, 1, 1); PRIO0();
    BAR();
    // P5
    STAGE(1,1,0,tt+3); STAGE(1,1,1,tt+3);
    BAR(); WAITLGKM0();
    PRIO1(); MFMA_Q(1, aN, bN0, bN1); PFA(aP, 1, 2); PRIO0();
    BAR();
    // P6
    STAGE(1,1,2,tt+3); STAGE(1,1,3,tt+3);
    BAR(); WAITLGKM0();
    PRIO1(); MFMA_Q(2, aP, bN0, bN1); PFA(aN, 1, 3); PRIO0();
    BAR();
    // P7: vmcnt retires P1..P4 loads = all of tile tt+2 (buf0)
    STAGE(1,0,0,tt+3); STAGE(1,0,2,tt+3);
    BAR(); WAITLGKM0(); VMCNT(6);
    PRIO1(); MFMA_Q(3, aN, bN0, bN1); PFB(bP0, bP1, 0); PFA(aP, 0, 0); PRIO0();
    BAR();
  }
  { // peeled final iteration: tiles NT-2 (buf0), NT-1 (buf1); no prefetch past K
    STAGE(1,0,1,NT-1); STAGE(1,0,3,NT-1);
    BAR(); WAITLGKM0();
    PRIO1(); MFMA_Q(0, aP, bP0, bP1); PFA(aN, 0, 1); PRIO0();
    BAR();
    BAR(); WAITLGKM0();
    PRIO1(); MFMA_Q(1, aN, bP0, bP1); PFA(aP, 0, 2); PRIO0();
    BAR();
    BAR(); WAITLGKM0();
    PRIO1(); MFMA_Q(2, aP, bP0, bP1); PFA(aN, 0, 3); PRIO0();
    BAR();
    BAR(); WAITLGKM0(); VMCNT(0);   // drain: tile NT-1 fully landed
    PRIO1(); MFMA_Q(3, aN, bP0, bP1); PFB(bN0, bN1, 1); PFA(aP, 1, 0); PRIO0();
    BAR();
    BAR(); WAITLGKM0();
    PRIO1(); MFMA_Q(0, aP, bN0, bN1); PFA(aN, 1, 1); PRIO0();
    BAR();
    BAR(); WAITLGKM0();
    PRIO1(); MFMA_Q(1, aN, bN0, bN1); PFA(aP, 1, 2); PRIO0();
    BAR();
    BAR(); WAITLGKM0();
    PRIO1(); MFMA_Q(2, aP, bN0, bN1); PFA(aN, 1, 3); PRIO0();
    BAR();
    BAR(); WAITLGKM0();
    PRIO1(); MFMA_Q(3, aN, bN0, bN1); PRIO0();
  }

  // epilogue: D reg r -> row = fq*4 + r, col = fr (m89-verified mapping)
  const int orow0 = bm*256 + wr*128;
  const int ocol0 = bn*256 + wc*64;
#pragma unroll
  for (int m=0;m<8;m++){
#pragma unroll
    for (int n=0;n<4;n++){
      const int col = ocol0 + n*16 + fr;
#pragma unroll
      for (int r=0;r<4;r++){
        const int row = orow0 + m*16 + fq*4 + r;
        float v = acc[m][n][r];
        if constexpr (EPI == 0){
          float o = (col < 1024) ? tanh_pi_(v) : sigmoid_(v);
          ((u16*)Cout)[(size_t)row*N + col] = f2bf(o);
        } else if constexpr (EPI == 1){
          v += bias[col];
          ((u16*)Cout)[(size_t)row*N + col] = f2bf(v * sigmoid_(v));
        } else {
          v += bias[col];
          ((float*)Cout)[(size_t)row*N + col] = v;
        }
      }
    }
  }
}

// ---------------- chunked lerp scan (res now bf16) ----------------
// res layout: [b][t][2048] bf16, col<1024 = theta' (pi*tanh), col>=1024 = s.
// recurrence: h_t = (1-s_t) h_{t-1} + s_t * theta'_t, h_{-1} = 0 (fp32 state)
__global__ __launch_bounds__(256) void scan_stage1(const u16* __restrict__ res,
                                                   float* __restrict__ sA,
                                                   float* __restrict__ sB,
                                                   float* __restrict__ sA2,
                                                   float* __restrict__ sB2){
  const int c     = (blockIdx.x & 3)*256 + threadIdx.x;
  const int chunk = (blockIdx.x >> 2) & (NCHUNK-1);
  const int b     = blockIdx.x >> 7;
  const u16* p = res + ((size_t)(b*T_LEN + chunk*CLEN))*2048 + c;
  float A = 1.f, Bv = 0.f;
#pragma unroll 4
  for (int t=0;t<CLEN-1;++t){
    float th = bf2f(p[0]);
    float s  = bf2f(p[1024]);
    float a  = 1.f - s;
    A  *= a;
    Bv  = a*Bv + s*th;
    p  += 2048;
  }
  const int idx = (b*NCHUNK + chunk)*1024 + c;
  sA2[idx] = A; sB2[idx] = Bv;         // transform through t0..t0+126
  {
    float th = bf2f(p[0]);
    float s  = bf2f(p[1024]);
    float a  = 1.f - s;
    A  *= a;
    Bv  = a*Bv + s*th;
  }
  sA[idx] = A; sB[idx] = Bv;
}

__global__ __launch_bounds__(256) void scan_stage2(const float* __restrict__ sA,
                                                   const float* __restrict__ sB,
                                                   float* __restrict__ Hp){
  const int g = blockIdx.x*256 + threadIdx.x;   // 4096 threads: b*1024+c
  const int b = g >> 10, c = g & 1023;
  float H = 0.f;
#pragma unroll
  for (int i=0;i<NCHUNK;++i){
    const int idx = (b*NCHUNK + i)*1024 + c;
    Hp[idx] = H;                 // state BEFORE chunk i
    H = sA[idx]*H + sB[idx];
  }
}

// ---------------- fused stage3 + depthwise causal conv(3) -> bf16 z ----------------
__global__ __launch_bounds__(256) void scan3_conv_k(const u16* __restrict__ res,
                                                    const float* __restrict__ Hp,
                                                    const float* __restrict__ sA2,
                                                    const float* __restrict__ sB2,
                                                    const float* __restrict__ cw,
                                                    const float* __restrict__ cb,
                                                    u16* __restrict__ z){
  const int c     = (blockIdx.x & 3)*256 + threadIdx.x;
  const int chunk = (blockIdx.x >> 2) & (NCHUNK-1);
  const int b     = blockIdx.x >> 7;
  const u16* p = res + ((size_t)(b*T_LEN + chunk*CLEN))*2048 + c;
  u16*       q = z   + ((size_t)(b*T_LEN + chunk*CLEN))*1024 + c;
  const int idx = (b*NCHUNK + chunk)*1024 + c;
  float H   = Hp[idx];           // = h[t0-1] (0 for chunk 0)
  float hm1 = H;
  float hm2 = 0.f;
  if (chunk > 0){
    const int pidx = idx - 1024;
    hm2 = sA2[pidx]*Hp[pidx] + sB2[pidx];   // = h[t0-2]
  }
  const float w0 = cw[3*c], w1 = cw[3*c+1], w2 = cw[3*c+2], bb = cb[c];
#pragma unroll 4
  for (int t=0;t<CLEN;++t){
    float th = bf2f(p[0]);
    float s  = bf2f(p[1024]);
    H = (1.f - s)*H + s*th;
    float v = H + bb + hm2*w0 + hm1*w1 + H*w2;
    q[0] = f2bf(v);
    hm2 = hm1; hm1 = H;
    p += 2048; q += 1024;
  }
}

// ---------------- in-place row RMSNorm (d=1024, one block per row) ----------------
__global__ __launch_bounds__(256) void rmsnorm_k(float* __restrict__ io,
                                                 const float* __restrict__ w){
  const int row = blockIdx.x;
  const int tid = threadIdx.x;
  float* p = io + (size_t)row*1024;
  float4 v = reinterpret_cast<const float4*>(p)[tid];
  float ss = v.x*v.x + v.y*v.y + v.z*v.z + v.w*v.w;
#pragma unroll
  for (int o=32; o>0; o>>=1) ss += __shfl_xor(ss, o, 64);
  __shared__ float red[4];
  if ((tid & 63) == 0) red[tid >> 6] = ss;
  __syncthreads();
  float tot = red[0] + red[1] + red[2] + red[3];
  float scale = rsqrtf(tot * (1.f/1024.f) + 1e-6f);
  float4 wv = reinterpret_cast<const float4*>(w)[tid];
  float4 o;
  o.x = v.x*scale*wv.x; o.y = v.y*scale*wv.y;
  o.z = v.z*scale*wv.z; o.w = v.w*scale*wv.w;
  reinterpret_cast<float4*>(p)[tid] = o;
}

extern "C" void kernel_launch(void* const* d_in, const int* in_sizes, int n_in,
                              void* d_out, int out_size, void* d_ws, size_t ws_size,
                              hipStream_t stream) {
  const float* x      = (const float*)d_in[0];
  const float* w_key  = (const float*)d_in[1];
  const float* conv_w = (const float*)d_in[2];
  const float* conv_b = (const float*)d_in[3];
  const float* w1     = (const float*)d_in[4];
  const float* b1     = (const float*)d_in[5];
  const float* w2     = (const float*)d_in[6];
  const float* b2     = (const float*)d_in[7];
  const float* norm_w = (const float*)d_in[8];
  float* out = (float*)d_out;
  char*  ws  = (char*)d_ws;

  // workspace layout (~118 MB)
  size_t off = 0;
  u16*   RES  = (u16*)  (ws + off); off += (size_t)M_TOT*2048*2; // bf16 res; reused as hid
  u16*   XB   = (u16*)  (ws + off); off += (size_t)M_TOT*1024*2; // x bf16; reused as z
  u16*   WK   = (u16*)  (ws + off); off += (size_t)2048*1024*2;
  u16*   W1B  = (u16*)  (ws + off); off += (size_t)2048*1024*2;
  u16*   W2B  = (u16*)  (ws + off); off += (size_t)1024*2048*2;
  float* SA   = (float*)(ws + off); off += (size_t)BATCH*NCHUNK*1024*4;
  float* SB   = (float*)(ws + off); off += (size_t)BATCH*NCHUNK*1024*4;
  float* SA2  = (float*)(ws + off); off += (size_t)BATCH*NCHUNK*1024*4;
  float* SB2  = (float*)(ws + off); off += (size_t)BATCH*NCHUNK*1024*4;
  float* HP   = (float*)(ws + off); off += (size_t)BATCH*NCHUNK*1024*4;
  u16* ZB  = XB;   // z aliases x_bf16 (dead after GEMM1)
  u16* HID = RES;  // hid aliases res (dead after scan3_conv_k)

  // allow 128 KiB dynamic LDS (idempotent host-side calls, graph-capture safe)
  hipFuncSetAttribute((const void*)gemm8p<0>, hipFuncAttributeMaxDynamicSharedMemorySize, 131072);
  hipFuncSetAttribute((const void*)gemm8p<1>, hipFuncAttributeMaxDynamicSharedMemorySize, 131072);
  hipFuncSetAttribute((const void*)gemm8p<2>, hipFuncAttributeMaxDynamicSharedMemorySize, 131072);

  // 1) fp32 -> bf16 converts
  cvt_bf16_k<<<(M_TOT*1024/4 + 255)/256, 256, 0, stream>>>(x,     XB,  M_TOT*1024/4);
  cvt_bf16_k<<<(2048*1024/4  + 255)/256, 256, 0, stream>>>(w_key, WK,  2048*1024/4);
  cvt_bf16_k<<<(2048*1024/4  + 255)/256, 256, 0, stream>>>(w1,    W1B, 2048*1024/4);
  cvt_bf16_k<<<(1024*2048/4  + 255)/256, 256, 0, stream>>>(w2,    W2B, 1024*2048/4);

  // 2) GEMM1 + activation epilogue -> res (bf16)
  gemm8p<0><<<(M_TOT/256)*(2048/256), 512, 131072, stream>>>(XB, WK, nullptr, RES, M_TOT, 2048, 1024);

  // 3) chunked scan; stage3 fused with depthwise conv -> z (bf16)
  scan_stage1<<<BATCH*NCHUNK*4, 256, 0, stream>>>(RES, SA, SB, SA2, SB2);
  scan_stage2<<<16, 256, 0, stream>>>(SA, SB, HP);
  scan3_conv_k<<<BATCH*NCHUNK*4, 256, 0, stream>>>(RES, HP, SA2, SB2, conv_w, conv_b, ZB);

  // 5) GEMM2 + silu -> hid (bf16)
  gemm8p<1><<<(M_TOT/256)*(2048/256), 512, 131072, stream>>>(ZB, W1B, b1, HID, M_TOT, 2048, 1024);

  // 6) GEMM3 + bias -> out (fp32)
  gemm8p<2><<<(M_TOT/256)*(1024/256), 512, 131072, stream>>>(HID, W2B, b2, out, M_TOT, 1024, 2048);

  // 7) in-place RMSNorm
  rmsnorm_k<<<M_TOT, 256, 0, stream>>>(out, norm_w);
}

// Round 5
// 314.544 us; speedup vs baseline: 1.4137x; 1.0073x over previous
//
#include <hip/hip_runtime.h>

typedef unsigned short u16;
typedef unsigned int u32;
typedef __attribute__((ext_vector_type(8))) short short8;  // 8 bf16 = 4 VGPR (MFMA A/B frag)
typedef __attribute__((ext_vector_type(4))) float f32x4;   // MFMA C/D frag

#define T_LEN 4096
#define BATCH 4
#define M_TOT (BATCH*T_LEN)   /* 16384 rows */
#define NCHUNK 32
#define CLEN 128              /* 4096/32 */

__device__ __forceinline__ u16 f2bf(float f){
  u32 u = __builtin_bit_cast(u32, f);
  u32 r = (u + 0x7FFFu + ((u >> 16) & 1u)) >> 16;   // RTN-even
  return (u16)r;
}
__device__ __forceinline__ float bf2f(u16 h){
  u32 u = ((u32)h) << 16; return __builtin_bit_cast(float, u);
}
__device__ __forceinline__ float sigmoid_(float v){ return 1.f/(1.f + __expf(-v)); }
__device__ __forceinline__ float tanh_pi_(float v){
  return 3.14159265358979323846f * (1.f - 2.f/(1.f + __expf(2.f*v)));
}

// ---------------- fp32 -> bf16 convert (vectorized x4) ----------------
__global__ __launch_bounds__(256) void cvt_bf16_k(const float* __restrict__ in,
                                                  u16* __restrict__ out, int n4){
  int g = blockIdx.x*256 + threadIdx.x;
  if (g >= n4) return;
  float4 v = reinterpret_cast<const float4*>(in)[g];
  reinterpret_cast<ushort4*>(out)[g] =
      make_ushort4(f2bf(v.x), f2bf(v.y), f2bf(v.z), f2bf(v.w));
}

// =================== 256x256 8-phase bf16 GEMM, reads-first pipeline ===================
// C[M,N] = A[M,K] @ B[N,K]^T. 512 thr = 8 waves (2M x 4N), BK=64, LDS 128 KiB dyn.
// r5 schedule: per phase [2 stages][bar][(vmcnt gate)][prio1][R ds_reads for NEXT
// phase][16 MFMA on current frags][prio0][SGB pin: DS_READ xR then MFMA x16][bar].
// In-order issue: reads FIRST so their LDS drain overlaps this phase's MFMA pipe
// time (the r4 order trapped reads behind MFMA pipe-full stalls). No explicit
// lgkmcnt(0): compiler emits counted lgkmcnt(N) throttles (m97/m201 pattern).
// vmcnt ledger (counted, never 0 in loop): VMCNT(6)@P3 retires through P0 = tile
// t+1 complete; VMCNT(8)@P6 through P2 = B(t+2) complete; VMCNT(6)@P7 through P4
// = A(t+2) complete. All stage-vs-read overwrite pairs re-audited safe.
#define BAR() __builtin_amdgcn_s_barrier()
#define VMCNT(n) asm volatile("s_waitcnt vmcnt(" #n ")" ::: "memory")
#define PRIO1() __builtin_amdgcn_s_setprio(1)
#define PRIO0() __builtin_amdgcn_s_setprio(0)
#define SGBPIN(R) do { __builtin_amdgcn_sched_group_barrier(0x100, R, 0); \
                       __builtin_amdgcn_sched_group_barrier(0x008, 16, 0); } while(0)

#define STAGE(buf, ab, q, kt) do { \
  const u16* _s = ((ab) ? Bb : Ab) + (size_t)(q)*rowK64 + (size_t)(kt)*64; \
  __builtin_amdgcn_global_load_lds( \
    (const __attribute__((address_space(1))) void*)_s, \
    (__attribute__((address_space(3))) void*)(smem + (buf)*65536 + (ab)*32768 + (q)*8192 + stb), \
    16, 0, 0); \
} while(0)

#define LDA(buf, m, kk) (*(const short8*)(smem + (buf)*65536 + aRow + (m)*2048 + ((kk) ? csw1 : csw0)))
#define LDB(buf, n, kk) (*(const short8*)(smem + (buf)*65536 + 32768 + bRow + (n)*2048 + ((kk) ? csw1 : csw0)))

#define PFA(dst, buf, q) do { \
  dst[0] = LDA(buf, 2*(q),   0); \
  dst[1] = LDA(buf, 2*(q),   1); \
  dst[2] = LDA(buf, 2*(q)+1, 0); \
  dst[3] = LDA(buf, 2*(q)+1, 1); } while(0)

// half of the B-frags: half 0 -> n=0,1 ; half 1 -> n=2,3  (4 reads each)
#define PFBH(d0, d1, buf, half) do { \
  d0[2*(half)]   = LDB(buf, 2*(half),   0); \
  d1[2*(half)]   = LDB(buf, 2*(half),   1); \
  d0[2*(half)+1] = LDB(buf, 2*(half)+1, 0); \
  d1[2*(half)+1] = LDB(buf, 2*(half)+1, 1); } while(0)

#define PFB(d0, d1, buf) do { PFBH(d0,d1,buf,0); PFBH(d0,d1,buf,1); } while(0)

#define MFMA_Q(q, A, B0, B1) do { _Pragma("unroll") \
  for (int n=0;n<4;n++){ \
    acc[2*(q)][n]   = __builtin_amdgcn_mfma_f32_16x16x32_bf16(A[0], B0[n], acc[2*(q)][n], 0,0,0); \
    acc[2*(q)][n]   = __builtin_amdgcn_mfma_f32_16x16x32_bf16(A[1], B1[n], acc[2*(q)][n], 0,0,0); \
    acc[2*(q)+1][n] = __builtin_amdgcn_mfma_f32_16x16x32_bf16(A[2], B0[n], acc[2*(q)+1][n], 0,0,0); \
    acc[2*(q)+1][n] = __builtin_amdgcn_mfma_f32_16x16x32_bf16(A[3], B1[n], acc[2*(q)+1][n], 0,0,0); \
  } } while(0)

// EPI 0: GEMM1 -> bf16 activated res (col<1024: pi*tanh, else sigmoid)
// EPI 1: GEMM2 -> bf16 silu(v + bias)
// EPI 2: GEMM3 -> fp32 v + bias
template<int EPI>
__global__ __launch_bounds__(512, 2) void gemm8p(
    const u16* __restrict__ Ag, const u16* __restrict__ Bg,
    const float* __restrict__ bias, void* __restrict__ Cout,
    int M, int N, int K)
{
  extern __shared__ __attribute__((aligned(16))) char smem[];
  const int tid = threadIdx.x;
  const int wid = tid >> 6, lane = tid & 63;
  const int wr = wid >> 2, wc = wid & 3;        // wave -> 128x64 output subtile
  const int fr = lane & 15, fq = lane >> 4;

  // T1: bijective XCD swizzle (nwg % 8 == 0 for all our launches)
  const int nbn = N >> 8;
  const int nwg = gridDim.x;
  const int bid = blockIdx.x;
  const int swzb = (bid & 7) * (nwg >> 3) + (bid >> 3);
  const int bm = swzb / nbn, bn = swzb - bm * nbn;

  const size_t rowK64 = (size_t)64 * K;
  // staging: thread t covers LDS bytes qbase + t*16 (linear); global source is
  // inverse-swizzled: row = t>>3 (within quarter), chunk = (t&7) ^ ((t>>3)&7)
  const u16* Ab = Ag + ((size_t)bm*256 + (tid>>3)) * K + ((tid & 7) ^ ((tid >> 3) & 7)) * 8;
  const u16* Bb = Bg + ((size_t)bn*256 + (tid>>3)) * K + ((tid & 7) ^ ((tid >> 3) & 7)) * 8;
  const u32 stb = (u32)(wid << 10);   // wave-uniform LDS staging base within quarter

  // swizzled ds_read addressing (row&7 == fr&7 since m*16 = 0 mod 8)
  const u32 aRow = (u32)(wr*128 + fr) * 128;
  const u32 bRow = (u32)(wc*64  + fr) * 128;
  const u32 csw0 = (u32)((fq*16)      ^ ((fr & 7) << 4));
  const u32 csw1 = (u32)((64 + fq*16) ^ ((fr & 7) << 4));

  f32x4 acc[8][4];
#pragma unroll
  for (int m=0;m<8;m++)
#pragma unroll
    for (int n=0;n<4;n++) acc[m][n] = f32x4{0.f,0.f,0.f,0.f};

  short8 bP0[4], bP1[4], bN0[4], bN1[4];   // B frags: current tile / next tile
  short8 aP[4], aN[4];                     // A frags: alternating per phase

  const int NT = K >> 6;   // K-tiles (16 or 32)

  // prologue: tile0 -> buf0 (8 loads); tile1 -> buf1 B all + A q0,q2 (6 loads)
  STAGE(0,1,0,0); STAGE(0,1,1,0); STAGE(0,1,2,0); STAGE(0,1,3,0);
  STAGE(0,0,0,0); STAGE(0,0,1,0); STAGE(0,0,2,0); STAGE(0,0,3,0);
  STAGE(1,1,0,1); STAGE(1,1,1,1); STAGE(1,1,2,1); STAGE(1,1,3,1);
  STAGE(1,0,0,1); STAGE(1,0,2,1);
  VMCNT(6);           // tile0 fully landed; 6 in flight (tile1 partial)
  BAR();
  PFB(bP0, bP1, 0);   // pre-read tile0 B + A-q0 (waited by P0's MFMA via compiler)
  PFA(aP, 0, 0);

  for (int i = 0; i < (NT>>1) - 1; ++i){
    const int tt = 2*i;
    // P0: MFMA buf0/q0
    STAGE(1,0,1,tt+1); STAGE(1,0,3,tt+1);
    BAR();
    PRIO1(); PFA(aN,0,1); MFMA_Q(0, aP, bP0, bP1); PRIO0(); SGBPIN(4);
    BAR();
    // P1
    STAGE(0,1,0,tt+2); STAGE(0,1,1,tt+2);
    BAR();
    PRIO1(); PFA(aP,0,2); MFMA_Q(1, aN, bP0, bP1); PRIO0(); SGBPIN(4);
    BAR();
    // P2
    STAGE(0,1,2,tt+2); STAGE(0,1,3,tt+2);
    BAR();
    PRIO1(); PFA(aN,0,3); MFMA_Q(2, aP, bP0, bP1); PRIO0(); SGBPIN(4);
    BAR();
    // P3: gate = tile t+1 complete (retires through P0)
    STAGE(0,0,0,tt+2); STAGE(0,0,2,tt+2);
    BAR();
    VMCNT(6);
    PRIO1(); PFA(aP,1,0); PFBH(bN0,bN1,1,0); MFMA_Q(3, aN, bP0, bP1); PRIO0(); SGBPIN(8);
    BAR();
    // P4: MFMA buf1/q0 (bN half1 read here, used late in this cluster — waited)
    STAGE(0,0,1,tt+2); STAGE(0,0,3,tt+2);
    BAR();
    PRIO1(); PFBH(bN0,bN1,1,1); PFA(aN,1,1); MFMA_Q(0, aP, bN0, bN1); PRIO0(); SGBPIN(8);
    BAR();
    // P5
    STAGE(1,1,0,tt+3); STAGE(1,1,1,tt+3);
    BAR();
    PRIO1(); PFA(aP,1,2); MFMA_Q(1, aN, bN0, bN1); PRIO0(); SGBPIN(4);
    BAR();
    // P6: gate = B(t+2) complete (retires through P2)
    STAGE(1,1,2,tt+3); STAGE(1,1,3,tt+3);
    BAR();
    VMCNT(8);
    PRIO1(); PFA(aN,1,3); PFBH(bP0,bP1,0,0); MFMA_Q(2, aP, bN0, bN1); PRIO0(); SGBPIN(8);
    BAR();
    // P7: gate = A(t+2) complete (retires through P4)
    STAGE(1,0,0,tt+3); STAGE(1,0,2,tt+3);
    BAR();
    VMCNT(6);
    PRIO1(); PFA(aP,0,0); PFBH(bP0,bP1,0,1); MFMA_Q(3, aN, bN0, bN1); PRIO0(); SGBPIN(8);
    BAR();
  }
  { // peeled final iteration: tiles NT-2 (buf0), NT-1 (buf1); no prefetch past K
    STAGE(1,0,1,NT-1); STAGE(1,0,3,NT-1);
    BAR();
    PRIO1(); PFA(aN,0,1); MFMA_Q(0, aP, bP0, bP1); PRIO0(); SGBPIN(4);
    BAR();
    BAR();
    PRIO1(); PFA(aP,0,2); MFMA_Q(1, aN, bP0, bP1); PRIO0(); SGBPIN(4);
    BAR();
    BAR();
    PRIO1(); PFA(aN,0,3); MFMA_Q(2, aP, bP0, bP1); PRIO0(); SGBPIN(4);
    BAR();
    BAR();
    VMCNT(0);   // drain: tile NT-1 fully landed
    PRIO1(); PFA(aP,1,0); PFBH(bN0,bN1,1,0); MFMA_Q(3, aN, bP0, bP1); PRIO0(); SGBPIN(8);
    BAR();
    BAR();
    PRIO1(); PFBH(bN0,bN1,1,1); PFA(aN,1,1); MFMA_Q(0, aP, bN0, bN1); PRIO0(); SGBPIN(8);
    BAR();
    BAR();
    PRIO1(); PFA(aP,1,2); MFMA_Q(1, aN, bN0, bN1); PRIO0(); SGBPIN(4);
    BAR();
    BAR();
    PRIO1(); PFA(aN,1,3); MFMA_Q(2, aP, bN0, bN1); PRIO0(); SGBPIN(4);
    BAR();
    BAR();
    PRIO1(); MFMA_Q(3, aN, bN0, bN1); PRIO0();
  }

  // epilogue: D reg r -> row = fq*4 + r, col = fr (m89-verified mapping)
  const int orow0 = bm*256 + wr*128;
  const int ocol0 = bn*256 + wc*64;
#pragma unroll
  for (int m=0;m<8;m++){
#pragma unroll
    for (int n=0;n<4;n++){
      const int col = ocol0 + n*16 + fr;
#pragma unroll
      for (int r=0;r<4;r++){
        const int row = orow0 + m*16 + fq*4 + r;
        float v = acc[m][n][r];
        if constexpr (EPI == 0){
          float o = (col < 1024) ? tanh_pi_(v) : sigmoid_(v);
          ((u16*)Cout)[(size_t)row*N + col] = f2bf(o);
        } else if constexpr (EPI == 1){
          v += bias[col];
          ((u16*)Cout)[(size_t)row*N + col] = f2bf(v * sigmoid_(v));
        } else {
          v += bias[col];
          ((float*)Cout)[(size_t)row*N + col] = v;
        }
      }
    }
  }
}

// ---------------- chunked lerp scan (res bf16) ----------------
// res layout: [b][t][2048] bf16, col<1024 = theta' (pi*tanh), col>=1024 = s.
// recurrence: h_t = (1-s_t) h_{t-1} + s_t * theta'_t, h_{-1} = 0 (fp32 state)
__global__ __launch_bounds__(256) void scan_stage1(const u16* __restrict__ res,
                                                   float* __restrict__ sA,
                                                   float* __restrict__ sB,
                                                   float* __restrict__ sA2,
                                                   float* __restrict__ sB2){
  const int c     = (blockIdx.x & 3)*256 + threadIdx.x;
  const int chunk = (blockIdx.x >> 2) & (NCHUNK-1);
  const int b     = blockIdx.x >> 7;
  const u16* p = res + ((size_t)(b*T_LEN + chunk*CLEN))*2048 + c;
  float A = 1.f, Bv = 0.f;
#pragma unroll 4
  for (int t=0;t<CLEN-1;++t){
    float th = bf2f(p[0]);
    float s  = bf2f(p[1024]);
    float a  = 1.f - s;
    A  *= a;
    Bv  = a*Bv + s*th;
    p  += 2048;
  }
  const int idx = (b*NCHUNK + chunk)*1024 + c;
  sA2[idx] = A; sB2[idx] = Bv;         // transform through t0..t0+126
  {
    float th = bf2f(p[0]);
    float s  = bf2f(p[1024]);
    float a  = 1.f - s;
    A  *= a;
    Bv  = a*Bv + s*th;
  }
  sA[idx] = A; sB[idx] = Bv;
}

__global__ __launch_bounds__(256) void scan_stage2(const float* __restrict__ sA,
                                                   const float* __restrict__ sB,
                                                   float* __restrict__ Hp){
  const int g = blockIdx.x*256 + threadIdx.x;   // 4096 threads: b*1024+c
  const int b = g >> 10, c = g & 1023;
  float H = 0.f;
#pragma unroll
  for (int i=0;i<NCHUNK;++i){
    const int idx = (b*NCHUNK + i)*1024 + c;
    Hp[idx] = H;                 // state BEFORE chunk i
    H = sA[idx]*H + sB[idx];
  }
}

// ---------------- fused stage3 + depthwise causal conv(3) -> bf16 z ----------------
__global__ __launch_bounds__(256) void scan3_conv_k(const u16* __restrict__ res,
                                                    const float* __restrict__ Hp,
                                                    const float* __restrict__ sA2,
                                                    const float* __restrict__ sB2,
                                                    const float* __restrict__ cw,
                                                    const float* __restrict__ cb,
                                                    u16* __restrict__ z){
  const int c     = (blockIdx.x & 3)*256 + threadIdx.x;
  const int chunk = (blockIdx.x >> 2) & (NCHUNK-1);
  const int b     = blockIdx.x >> 7;
  const u16* p = res + ((size_t)(b*T_LEN + chunk*CLEN))*2048 + c;
  u16*       q = z   + ((size_t)(b*T_LEN + chunk*CLEN))*1024 + c;
  const int idx = (b*NCHUNK + chunk)*1024 + c;
  float H   = Hp[idx];           // = h[t0-1] (0 for chunk 0)
  float hm1 = H;
  float hm2 = 0.f;
  if (chunk > 0){
    const int pidx = idx - 1024;
    hm2 = sA2[pidx]*Hp[pidx] + sB2[pidx];   // = h[t0-2]
  }
  const float w0 = cw[3*c], w1 = cw[3*c+1], w2 = cw[3*c+2], bb = cb[c];
#pragma unroll 4
  for (int t=0;t<CLEN;++t){
    float th = bf2f(p[0]);
    float s  = bf2f(p[1024]);
    H = (1.f - s)*H + s*th;
    float v = H + bb + hm2*w0 + hm1*w1 + H*w2;
    q[0] = f2bf(v);
    hm2 = hm1; hm1 = H;
    p += 2048; q += 1024;
  }
}

// ---------------- in-place row RMSNorm (d=1024, one block per row) ----------------
__global__ __launch_bounds__(256) void rmsnorm_k(float* __restrict__ io,
                                                 const float* __restrict__ w){
  const int row = blockIdx.x;
  const int tid = threadIdx.x;
  float* p = io + (size_t)row*1024;
  float4 v = reinterpret_cast<const float4*>(p)[tid];
  float ss = v.x*v.x + v.y*v.y + v.z*v.z + v.w*v.w;
#pragma unroll
  for (int o=32; o>0; o>>=1) ss += __shfl_xor(ss, o, 64);
  __shared__ float red[4];
  if ((tid & 63) == 0) red[tid >> 6] = ss;
  __syncthreads();
  float tot = red[0] + red[1] + red[2] + red[3];
  float scale = rsqrtf(tot * (1.f/1024.f) + 1e-6f);
  float4 wv = reinterpret_cast<const float4*>(w)[tid];
  float4 o;
  o.x = v.x*scale*wv.x; o.y = v.y*scale*wv.y;
  o.z = v.z*scale*wv.z; o.w = v.w*scale*wv.w;
  reinterpret_cast<float4*>(p)[tid] = o;
}

extern "C" void kernel_launch(void* const* d_in, const int* in_sizes, int n_in,
                              void* d_out, int out_size, void* d_ws, size_t ws_size,
                              hipStream_t stream) {
  const float* x      = (const float*)d_in[0];
  const float* w_key  = (const float*)d_in[1];
  const float* conv_w = (const float*)d_in[2];
  const float* conv_b = (const float*)d_in[3];
  const float* w1     = (const float*)d_in[4];
  const float* b1     = (const float*)d_in[5];
  const float* w2     = (const float*)d_in[6];
  const float* b2     = (const float*)d_in[7];
  const float* norm_w = (const float*)d_in[8];
  float* out = (float*)d_out;
  char*  ws  = (char*)d_ws;

  // workspace layout (~118 MB)
  size_t off = 0;
  u16*   RES  = (u16*)  (ws + off); off += (size_t)M_TOT*2048*2; // bf16 res; reused as hid
  u16*   XB   = (u16*)  (ws + off); off += (size_t)M_TOT*1024*2; // x bf16; reused as z
  u16*   WK   = (u16*)  (ws + off); off += (size_t)2048*1024*2;
  u16*   W1B  = (u16*)  (ws + off); off += (size_t)2048*1024*2;
  u16*   W2B  = (u16*)  (ws + off); off += (size_t)1024*2048*2;
  float* SA   = (float*)(ws + off); off += (size_t)BATCH*NCHUNK*1024*4;
  float* SB   = (float*)(ws + off); off += (size_t)BATCH*NCHUNK*1024*4;
  float* SA2  = (float*)(ws + off); off += (size_t)BATCH*NCHUNK*1024*4;
  float* SB2  = (float*)(ws + off); off += (size_t)BATCH*NCHUNK*1024*4;
  float* HP   = (float*)(ws + off); off += (size_t)BATCH*NCHUNK*1024*4;
  u16* ZB  = XB;   // z aliases x_bf16 (dead after GEMM1)
  u16* HID = RES;  // hid aliases res (dead after scan3_conv_k)

  // allow 128 KiB dynamic LDS (idempotent host-side calls, graph-capture safe)
  hipFuncSetAttribute((const void*)gemm8p<0>, hipFuncAttributeMaxDynamicSharedMemorySize, 131072);
  hipFuncSetAttribute((const void*)gemm8p<1>, hipFuncAttributeMaxDynamicSharedMemorySize, 131072);
  hipFuncSetAttribute((const void*)gemm8p<2>, hipFuncAttributeMaxDynamicSharedMemorySize, 131072);

  // 1) fp32 -> bf16 converts
  cvt_bf16_k<<<(M_TOT*1024/4 + 255)/256, 256, 0, stream>>>(x,     XB,  M_TOT*1024/4);
  cvt_bf16_k<<<(2048*1024/4  + 255)/256, 256, 0, stream>>>(w_key, WK,  2048*1024/4);
  cvt_bf16_k<<<(2048*1024/4  + 255)/256, 256, 0, stream>>>(w1,    W1B, 2048*1024/4);
  cvt_bf16_k<<<(1024*2048/4  + 255)/256, 256, 0, stream>>>(w2,    W2B, 1024*2048/4);

  // 2) GEMM1 + activation epilogue -> res (bf16)
  gemm8p<0><<<(M_TOT/256)*(2048/256), 512, 131072, stream>>>(XB, WK, nullptr, RES, M_TOT, 2048, 1024);

  // 3) chunked scan; stage3 fused with depthwise conv -> z (bf16)
  scan_stage1<<<BATCH*NCHUNK*4, 256, 0, stream>>>(RES, SA, SB, SA2, SB2);
  scan_stage2<<<16, 256, 0, stream>>>(SA, SB, HP);
  scan3_conv_k<<<BATCH*NCHUNK*4, 256, 0, stream>>>(RES, HP, SA2, SB2, conv_w, conv_b, ZB);

  // 5) GEMM2 + silu -> hid (bf16)
  gemm8p<1><<<(M_TOT/256)*(2048/256), 512, 131072, stream>>>(ZB, W1B, b1, HID, M_TOT, 2048, 1024);

  // 6) GEMM3 + bias -> out (fp32)
  gemm8p<2><<<(M_TOT/256)*(1024/256), 512, 131072, stream>>>(HID, W2B, b2, out, M_TOT, 1024, 2048);

  // 7) in-place RMSNorm
  rmsnorm_k<<<M_TOT, 256, 0, stream>>>(out, norm_w);
}

// Round 6
// 308.314 us; speedup vs baseline: 1.4423x; 1.0202x over previous
//
#include <hip/hip_runtime.h>

typedef unsigned short u16;
typedef unsigned int u32;
typedef __attribute__((ext_vector_type(8))) short short8;  // 8 bf16 = 4 VGPR (MFMA A/B frag)
typedef __attribute__((ext_vector_type(4))) float f32x4;   // MFMA C/D frag

#define T_LEN 4096
#define BATCH 4
#define M_TOT (BATCH*T_LEN)   /* 16384 rows */
#define NCHUNK 64
#define CLEN 64               /* 4096/64 */

__device__ __forceinline__ u16 f2bf(float f){
  u32 u = __builtin_bit_cast(u32, f);
  u32 r = (u + 0x7FFFu + ((u >> 16) & 1u)) >> 16;   // RTN-even
  return (u16)r;
}
__device__ __forceinline__ float bf2f(u16 h){
  u32 u = ((u32)h) << 16; return __builtin_bit_cast(float, u);
}
__device__ __forceinline__ float sigmoid_(float v){ return 1.f/(1.f + __expf(-v)); }
__device__ __forceinline__ float tanh_pi_(float v){
  return 3.14159265358979323846f * (1.f - 2.f/(1.f + __expf(2.f*v)));
}

// ---------------- fp32 -> bf16 convert (vectorized x4) ----------------
__global__ __launch_bounds__(256) void cvt_bf16_k(const float* __restrict__ in,
                                                  u16* __restrict__ out, int n4){
  int g = blockIdx.x*256 + threadIdx.x;
  if (g >= n4) return;
  float4 v = reinterpret_cast<const float4*>(in)[g];
  reinterpret_cast<ushort4*>(out)[g] =
      make_ushort4(f2bf(v.x), f2bf(v.y), f2bf(v.z), f2bf(v.w));
}

// ======= 256x256 8-phase bf16 GEMM — m201-exact phase content + kk-outer MFMA =======
// C[M,N] = A[M,K] @ B[N,K]^T. 512 thr = 8 waves (2M x 4N), BK=64, LDS 128 KiB dyn.
// Phases organized by C-quadrant (mh,nh) x full K=64, JIT reads consumed same phase:
//   P0/P4 (0,0): 12 reads (A m0-3 x2kk + B n0-1 x2kk) + lgkmcnt(8) throttle
//   P1/P5 (0,1):  4 reads (B n2-3)      P2/P6 (1,0): 8 reads (A m4-7)
//   P3/P7 (1,1):  0 reads (all frags reused)
// MFMA order kk-OUTER: within a quadrant, 8 independent accs per kk group ->
// accumulator reuse distance 8 (was 1: back-to-back same-acc pairs all rounds).
// Stage map (2 gload_lds/phase, every target >=1 full barrier after last reader):
//   P0: A1,A3(t+1) | P1: A0,A2(t+2) | P2: B0,B1(t+2) | P3: B2,B3(t+2)
//   P4: A1,A3(t+2) | P5: A0,A2(t+3) | P6: B0,B1(t+3) | P7: B2,B3(t+3)
// Gates: VMCNT(6)@P3 retires prevP5..P0 = tile t+1 complete (P4 reads buf1);
//        VMCNT(6)@P7 retires P1..P4 = tile t+2 complete (next P0 reads buf0).
// LDS swizzle: byte ^= (row&7)<<4 on reads; inverse-swizzled GLOBAL src on stages.
#define BAR() __builtin_amdgcn_s_barrier()
#define VMCNT(n) asm volatile("s_waitcnt vmcnt(" #n ")" ::: "memory")
#define LGKM0() asm volatile("s_waitcnt lgkmcnt(0)" ::: "memory")
#define LGKM8() asm volatile("s_waitcnt lgkmcnt(8)" ::: "memory")
#define FEN() asm volatile("" ::: "memory")
#define PRIO1() __builtin_amdgcn_s_setprio(1)
#define PRIO0() __builtin_amdgcn_s_setprio(0)

#define STAGE(buf, ab, q, kt) do { \
  const u16* _s = ((ab) ? Bb : Ab) + (size_t)(q)*rowK64 + (size_t)(kt)*64; \
  __builtin_amdgcn_global_load_lds( \
    (const __attribute__((address_space(1))) void*)_s, \
    (__attribute__((address_space(3))) void*)(smem + (buf)*65536 + (ab)*32768 + (q)*8192 + stb), \
    16, 0, 0); \
} while(0)

#define LDA(base, m, kk) (*(const short8*)((base) + (m)*2048 + ((kk) ? csw1 : csw0)))
#define LDB(base, n, kk) (*(const short8*)((base) + (n)*2048 + ((kk) ? csw1 : csw0)))

#define RD_A(base, h) do { _Pragma("unroll") \
  for (int ml=0; ml<4; ml++){ \
    aF[ml*2+0] = LDA(base, 4*(h)+ml, 0); \
    aF[ml*2+1] = LDA(base, 4*(h)+ml, 1); } } while(0)

#define RD_B(base, h) do { _Pragma("unroll") \
  for (int nl=0; nl<2; nl++){ \
    bF[(h)*4+nl*2+0] = LDB(base, 2*(h)+nl, 0); \
    bF[(h)*4+nl*2+1] = LDB(base, 2*(h)+nl, 1); } } while(0)

#define MFMAQ(mh, nh) do { _Pragma("unroll") \
  for (int kk=0; kk<2; kk++) \
  _Pragma("unroll") \
  for (int ml=0; ml<4; ml++) \
  _Pragma("unroll") \
  for (int nl=0; nl<2; nl++) \
    acc[4*(mh)+ml][2*(nh)+nl] = __builtin_amdgcn_mfma_f32_16x16x32_bf16( \
      aF[ml*2+kk], bF[(nh)*4+nl*2+kk], acc[4*(mh)+ml][2*(nh)+nl], 0,0,0); \
} while(0)

// EPI 0: GEMM1 -> bf16 activated res (col<1024: pi*tanh, else sigmoid)
// EPI 1: GEMM2 -> bf16 silu(v + bias)
// EPI 2: GEMM3 -> fp32 v + bias
template<int EPI>
__global__ __launch_bounds__(512, 2) void gemm8p(
    const u16* __restrict__ Ag, const u16* __restrict__ Bg,
    const float* __restrict__ bias, void* __restrict__ Cout,
    int M, int N, int K)
{
  extern __shared__ __attribute__((aligned(16))) char smem[];
  const int tid = threadIdx.x;
  const int wid = tid >> 6, lane = tid & 63;
  const int wr = wid >> 2, wc = wid & 3;        // wave -> 128x64 output subtile
  const int fr = lane & 15, fq = lane >> 4;

  // T1: bijective XCD swizzle (nwg % 8 == 0 for all our launches)
  const int nbn = N >> 8;
  const int nwg = gridDim.x;
  const int bid = blockIdx.x;
  const int swzb = (bid & 7) * (nwg >> 3) + (bid >> 3);
  const int bm = swzb / nbn, bn = swzb - bm * nbn;

  const size_t rowK64 = (size_t)64 * K;
  // staging: thread t covers LDS bytes qbase + t*16 (linear); global source is
  // inverse-swizzled: row = t>>3 (within quarter), chunk = (t&7) ^ ((t>>3)&7)
  const u16* Ab = Ag + ((size_t)bm*256 + (tid>>3)) * K + ((tid & 7) ^ ((tid >> 3) & 7)) * 8;
  const u16* Bb = Bg + ((size_t)bn*256 + (tid>>3)) * K + ((tid & 7) ^ ((tid >> 3) & 7)) * 8;
  const u32 stb = (u32)(wid << 10);   // wave-uniform LDS staging base within quarter

  // swizzled ds_read addressing (row&7 == fr&7 since m*16 = 0 mod 8)
  const u32 csw0 = (u32)((fq*16)      ^ ((fr & 7) << 4));
  const u32 csw1 = (u32)((64 + fq*16) ^ ((fr & 7) << 4));
  const char* aB0 = smem +         (u32)(wr*128 + fr) * 128;
  const char* aB1 = aB0 + 65536;
  const char* bB0 = smem + 32768 + (u32)(wc*64  + fr) * 128;
  const char* bB1 = bB0 + 65536;

  f32x4 acc[8][4];
#pragma unroll
  for (int m=0;m<8;m++)
#pragma unroll
    for (int n=0;n<4;n++) acc[m][n] = f32x4{0.f,0.f,0.f,0.f};

  short8 aF[8];   // current quadrant-row A frags (m-half x 2kk)
  short8 bF[8];   // B frags, both n-halves x 2kk (live across the tile)

  const int NT = K >> 6;   // K-tiles (16 or 32)

  // prologue: tile0 all 8; tile1 A0,A2 + B all (6); gate retires tile0
  STAGE(0,0,0,0); STAGE(0,0,1,0); STAGE(0,0,2,0); STAGE(0,0,3,0);
  STAGE(0,1,0,0); STAGE(0,1,1,0); STAGE(0,1,2,0); STAGE(0,1,3,0);
  STAGE(1,0,0,1); STAGE(1,0,2,1);
  STAGE(1,1,0,1); STAGE(1,1,1,1); STAGE(1,1,2,1); STAGE(1,1,3,1);
  VMCNT(6);
  BAR();

  for (int i = 0; i < (NT>>1) - 1; ++i){
    const int tt = 2*i;
    // P0 (buf0, quad 0,0): 12 reads + lgkm8 pace
    RD_A(aB0,0); RD_B(bB0,0); FEN();
    STAGE(1,0,1,tt+1); STAGE(1,0,3,tt+1);
    LGKM8();
    BAR(); LGKM0();
    PRIO1(); MFMAQ(0,0); PRIO0();
    BAR();
    // P1 (0,1): 4 reads
    RD_B(bB0,1); FEN();
    STAGE(0,0,0,tt+2); STAGE(0,0,2,tt+2);
    BAR(); LGKM0();
    PRIO1(); MFMAQ(0,1); PRIO0();
    BAR();
    // P2 (1,0): 8 reads
    RD_A(aB0,1); FEN();
    STAGE(0,1,0,tt+2); STAGE(0,1,1,tt+2);
    BAR(); LGKM0();
    PRIO1(); MFMAQ(1,0); PRIO0();
    BAR();
    // P3 (1,1): 0 reads; gate tile t+1
    STAGE(0,1,2,tt+2); STAGE(0,1,3,tt+2);
    BAR();
    PRIO1(); MFMAQ(1,1); PRIO0();
    VMCNT(6);
    BAR();
    // P4 (buf1, quad 0,0)
    RD_A(aB1,0); RD_B(bB1,0); FEN();
    STAGE(0,0,1,tt+2); STAGE(0,0,3,tt+2);
    LGKM8();
    BAR(); LGKM0();
    PRIO1(); MFMAQ(0,0); PRIO0();
    BAR();
    // P5 (0,1)
    RD_B(bB1,1); FEN();
    STAGE(1,0,0,tt+3); STAGE(1,0,2,tt+3);
    BAR(); LGKM0();
    PRIO1(); MFMAQ(0,1); PRIO0();
    BAR();
    // P6 (1,0)
    RD_A(aB1,1); FEN();
    STAGE(1,1,0,tt+3); STAGE(1,1,1,tt+3);
    BAR(); LGKM0();
    PRIO1(); MFMAQ(1,0); PRIO0();
    BAR();
    // P7 (1,1): gate tile t+2
    STAGE(1,1,2,tt+3); STAGE(1,1,3,tt+3);
    BAR();
    PRIO1(); MFMAQ(1,1); PRIO0();
    VMCNT(6);
    BAR();
  }
  { // peeled final iteration: tiles NT-2 (buf0), NT-1 (buf1)
    RD_A(aB0,0); RD_B(bB0,0); FEN();
    STAGE(1,0,1,NT-1); STAGE(1,0,3,NT-1);
    LGKM8();
    BAR(); LGKM0();
    PRIO1(); MFMAQ(0,0); PRIO0();
    BAR();
    RD_B(bB0,1); FEN();
    BAR(); LGKM0();
    PRIO1(); MFMAQ(0,1); PRIO0();
    BAR();
    RD_A(aB0,1); FEN();
    BAR(); LGKM0();
    PRIO1(); MFMAQ(1,0); PRIO0();
    BAR();
    BAR();
    PRIO1(); MFMAQ(1,1); PRIO0();
    VMCNT(0);     // drain: tile NT-1 fully landed
    BAR();
    RD_A(aB1,0); RD_B(bB1,0); FEN();
    BAR(); LGKM0();
    PRIO1(); MFMAQ(0,0); PRIO0();
    BAR();
    RD_B(bB1,1); FEN();
    BAR(); LGKM0();
    PRIO1(); MFMAQ(0,1); PRIO0();
    BAR();
    RD_A(aB1,1); FEN();
    BAR(); LGKM0();
    PRIO1(); MFMAQ(1,0); PRIO0();
    BAR();
    PRIO1(); MFMAQ(1,1); PRIO0();
  }

  // epilogue: D reg r -> row = fq*4 + r, col = fr (m89-verified mapping)
  const int orow0 = bm*256 + wr*128;
  const int ocol0 = bn*256 + wc*64;
#pragma unroll
  for (int m=0;m<8;m++){
#pragma unroll
    for (int n=0;n<4;n++){
      const int col = ocol0 + n*16 + fr;
#pragma unroll
      for (int r=0;r<4;r++){
        const int row = orow0 + m*16 + fq*4 + r;
        float v = acc[m][n][r];
        if constexpr (EPI == 0){
          float o = (col < 1024) ? tanh_pi_(v) : sigmoid_(v);
          ((u16*)Cout)[(size_t)row*N + col] = f2bf(o);
        } else if constexpr (EPI == 1){
          v += bias[col];
          ((u16*)Cout)[(size_t)row*N + col] = f2bf(v * sigmoid_(v));
        } else {
          v += bias[col];
          ((float*)Cout)[(size_t)row*N + col] = v;
        }
      }
    }
  }
}

// ---------------- chunked lerp scan (res bf16, 2 channels/thread) ----------------
// res layout: [b][t][2048] bf16, col<1024 = theta' (pi*tanh), col>=1024 = s.
// recurrence: h_t = (1-s_t) h_{t-1} + s_t * theta'_t, h_{-1} = 0 (fp32 state)
__global__ __launch_bounds__(256) void scan_stage1(const u16* __restrict__ res,
                                                   float* __restrict__ sA,
                                                   float* __restrict__ sB,
                                                   float* __restrict__ sA2,
                                                   float* __restrict__ sB2){
  const int c0    = ((blockIdx.x & 1)*256 + threadIdx.x)*2;
  const int chunk = (blockIdx.x >> 1) & (NCHUNK-1);
  const int b     = blockIdx.x >> 7;
  const u16* p = res + ((size_t)(b*T_LEN + chunk*CLEN))*2048 + c0;
  float A0=1.f, B0v=0.f, A1=1.f, B1v=0.f;
#pragma unroll 4
  for (int t=0;t<CLEN-1;++t){
    ushort2 th = *reinterpret_cast<const ushort2*>(p);
    ushort2 sg = *reinterpret_cast<const ushort2*>(p+1024);
    float s0 = bf2f(sg.x), s1 = bf2f(sg.y);
    float a0 = 1.f - s0,   a1 = 1.f - s1;
    A0 *= a0;  B0v = a0*B0v + s0*bf2f(th.x);
    A1 *= a1;  B1v = a1*B1v + s1*bf2f(th.y);
    p += 2048;
  }
  const int idx = (b*NCHUNK + chunk)*1024 + c0;
  *reinterpret_cast<float2*>(&sA2[idx]) = make_float2(A0, A1);
  *reinterpret_cast<float2*>(&sB2[idx]) = make_float2(B0v, B1v);
  {
    ushort2 th = *reinterpret_cast<const ushort2*>(p);
    ushort2 sg = *reinterpret_cast<const ushort2*>(p+1024);
    float s0 = bf2f(sg.x), s1 = bf2f(sg.y);
    float a0 = 1.f - s0,   a1 = 1.f - s1;
    A0 *= a0;  B0v = a0*B0v + s0*bf2f(th.x);
    A1 *= a1;  B1v = a1*B1v + s1*bf2f(th.y);
  }
  *reinterpret_cast<float2*>(&sA[idx]) = make_float2(A0, A1);
  *reinterpret_cast<float2*>(&sB[idx]) = make_float2(B0v, B1v);
}

__global__ __launch_bounds__(256) void scan_stage2(const float* __restrict__ sA,
                                                   const float* __restrict__ sB,
                                                   float* __restrict__ Hp){
  const int g = blockIdx.x*256 + threadIdx.x;   // 4096 threads: b*1024+c
  const int b = g >> 10, c = g & 1023;
  float H = 0.f;
#pragma unroll
  for (int i=0;i<NCHUNK;++i){
    const int idx = (b*NCHUNK + i)*1024 + c;
    Hp[idx] = H;                 // state BEFORE chunk i
    H = sA[idx]*H + sB[idx];
  }
}

// ------- fused stage3 + depthwise causal conv(3) -> bf16 z (2 channels/thread) -------
__global__ __launch_bounds__(256) void scan3_conv_k(const u16* __restrict__ res,
                                                    const float* __restrict__ Hp,
                                                    const float* __restrict__ sA2,
                                                    const float* __restrict__ sB2,
                                                    const float* __restrict__ cw,
                                                    const float* __restrict__ cb,
                                                    u16* __restrict__ z){
  const int c0    = ((blockIdx.x & 1)*256 + threadIdx.x)*2;
  const int chunk = (blockIdx.x >> 1) & (NCHUNK-1);
  const int b     = blockIdx.x >> 7;
  const u16* p = res + ((size_t)(b*T_LEN + chunk*CLEN))*2048 + c0;
  u16*       q = z   + ((size_t)(b*T_LEN + chunk*CLEN))*1024 + c0;
  const int idx = (b*NCHUNK + chunk)*1024 + c0;
  float H0 = Hp[idx], H1 = Hp[idx+1];          // h[t0-1] (0 for chunk 0)
  float hm1_0 = H0, hm1_1 = H1;
  float hm2_0 = 0.f, hm2_1 = 0.f;
  if (chunk > 0){
    const int pidx = idx - 1024;
    hm2_0 = sA2[pidx]*Hp[pidx] + sB2[pidx];        // h[t0-2]
    hm2_1 = sA2[pidx+1]*Hp[pidx+1] + sB2[pidx+1];
  }
  const float w0_0 = cw[3*c0],   w1_0 = cw[3*c0+1], w2_0 = cw[3*c0+2], bb0 = cb[c0];
  const float w0_1 = cw[3*c0+3], w1_1 = cw[3*c0+4], w2_1 = cw[3*c0+5], bb1 = cb[c0+1];
#pragma unroll 4
  for (int t=0;t<CLEN;++t){
    ushort2 th = *reinterpret_cast<const ushort2*>(p);
    ushort2 sg = *reinterpret_cast<const ushort2*>(p+1024);
    float s0 = bf2f(sg.x), s1 = bf2f(sg.y);
    H0 = (1.f - s0)*H0 + s0*bf2f(th.x);
    H1 = (1.f - s1)*H1 + s1*bf2f(th.y);
    float v0 = H0 + bb0 + hm2_0*w0_0 + hm1_0*w1_0 + H0*w2_0;
    float v1 = H1 + bb1 + hm2_1*w0_1 + hm1_1*w1_1 + H1*w2_1;
    *reinterpret_cast<ushort2*>(q) = make_ushort2(f2bf(v0), f2bf(v1));
    hm2_0 = hm1_0; hm1_0 = H0;
    hm2_1 = hm1_1; hm1_1 = H1;
    p += 2048; q += 1024;
  }
}

// ---------------- in-place row RMSNorm (d=1024, one block per row) ----------------
__global__ __launch_bounds__(256) void rmsnorm_k(float* __restrict__ io,
                                                 const float* __restrict__ w){
  const int row = blockIdx.x;
  const int tid = threadIdx.x;
  float* p = io + (size_t)row*1024;
  float4 v = reinterpret_cast<const float4*>(p)[tid];
  float ss = v.x*v.x + v.y*v.y + v.z*v.z + v.w*v.w;
#pragma unroll
  for (int o=32; o>0; o>>=1) ss += __shfl_xor(ss, o, 64);
  __shared__ float red[4];
  if ((tid & 63) == 0) red[tid >> 6] = ss;
  __syncthreads();
  float tot = red[0] + red[1] + red[2] + red[3];
  float scale = rsqrtf(tot * (1.f/1024.f) + 1e-6f);
  float4 wv = reinterpret_cast<const float4*>(w)[tid];
  float4 o;
  o.x = v.x*scale*wv.x; o.y = v.y*scale*wv.y;
  o.z = v.z*scale*wv.z; o.w = v.w*scale*wv.w;
  reinterpret_cast<float4*>(p)[tid] = o;
}

extern "C" void kernel_launch(void* const* d_in, const int* in_sizes, int n_in,
                              void* d_out, int out_size, void* d_ws, size_t ws_size,
                              hipStream_t stream) {
  const float* x      = (const float*)d_in[0];
  const float* w_key  = (const float*)d_in[1];
  const float* conv_w = (const float*)d_in[2];
  const float* conv_b = (const float*)d_in[3];
  const float* w1     = (const float*)d_in[4];
  const float* b1     = (const float*)d_in[5];
  const float* w2     = (const float*)d_in[6];
  const float* b2     = (const float*)d_in[7];
  const float* norm_w = (const float*)d_in[8];
  float* out = (float*)d_out;
  char*  ws  = (char*)d_ws;

  // workspace layout (~120 MB)
  size_t off = 0;
  u16*   RES  = (u16*)  (ws + off); off += (size_t)M_TOT*2048*2; // bf16 res; reused as hid
  u16*   XB   = (u16*)  (ws + off); off += (size_t)M_TOT*1024*2; // x bf16; reused as z
  u16*   WK   = (u16*)  (ws + off); off += (size_t)2048*1024*2;
  u16*   W1B  = (u16*)  (ws + off); off += (size_t)2048*1024*2;
  u16*   W2B  = (u16*)  (ws + off); off += (size_t)1024*2048*2;
  float* SA   = (float*)(ws + off); off += (size_t)BATCH*NCHUNK*1024*4;
  float* SB   = (float*)(ws + off); off += (size_t)BATCH*NCHUNK*1024*4;
  float* SA2  = (float*)(ws + off); off += (size_t)BATCH*NCHUNK*1024*4;
  float* SB2  = (float*)(ws + off); off += (size_t)BATCH*NCHUNK*1024*4;
  float* HP   = (float*)(ws + off); off += (size_t)BATCH*NCHUNK*1024*4;
  u16* ZB  = XB;   // z aliases x_bf16 (dead after GEMM1)
  u16* HID = RES;  // hid aliases res (dead after scan3_conv_k)

  // allow 128 KiB dynamic LDS (idempotent host-side calls, graph-capture safe)
  hipFuncSetAttribute((const void*)gemm8p<0>, hipFuncAttributeMaxDynamicSharedMemorySize, 131072);
  hipFuncSetAttribute((const void*)gemm8p<1>, hipFuncAttributeMaxDynamicSharedMemorySize, 131072);
  hipFuncSetAttribute((const void*)gemm8p<2>, hipFuncAttributeMaxDynamicSharedMemorySize, 131072);

  // 1) fp32 -> bf16 converts
  cvt_bf16_k<<<(M_TOT*1024/4 + 255)/256, 256, 0, stream>>>(x,     XB,  M_TOT*1024/4);
  cvt_bf16_k<<<(2048*1024/4  + 255)/256, 256, 0, stream>>>(w_key, WK,  2048*1024/4);
  cvt_bf16_k<<<(2048*1024/4  + 255)/256, 256, 0, stream>>>(w1,    W1B, 2048*1024/4);
  cvt_bf16_k<<<(1024*2048/4  + 255)/256, 256, 0, stream>>>(w2,    W2B, 1024*2048/4);

  // 2) GEMM1 + activation epilogue -> res (bf16)
  gemm8p<0><<<(M_TOT/256)*(2048/256), 512, 131072, stream>>>(XB, WK, nullptr, RES, M_TOT, 2048, 1024);

  // 3) chunked scan; stage3 fused with depthwise conv -> z (bf16)
  scan_stage1<<<BATCH*NCHUNK*2, 256, 0, stream>>>(RES, SA, SB, SA2, SB2);
  scan_stage2<<<16, 256, 0, stream>>>(SA, SB, HP);
  scan3_conv_k<<<BATCH*NCHUNK*2, 256, 0, stream>>>(RES, HP, SA2, SB2, conv_w, conv_b, ZB);

  // 5) GEMM2 + silu -> hid (bf16)
  gemm8p<1><<<(M_TOT/256)*(2048/256), 512, 131072, stream>>>(ZB, W1B, b1, HID, M_TOT, 2048, 1024);

  // 6) GEMM3 + bias -> out (fp32)
  gemm8p<2><<<(M_TOT/256)*(1024/256), 512, 131072, stream>>>(HID, W2B, b2, out, M_TOT, 1024, 2048);

  // 7) in-place RMSNorm
  rmsnorm_k<<<M_TOT, 256, 0, stream>>>(out, norm_w);
}